// Round 8
// baseline (1162.632 us; speedup 1.0000x reference)
//
#include <hip/hip_runtime.h>
#include <hip/hip_bf16.h>

typedef __hip_bfloat16 bf16;

#define NN 16384          // gate nodes
#define BBG 64            // graphs
#define EE 49152          // directed edges (no self loops)
#define ET (EE + NN)      // edges + self loops = 65536
#define DD 512            // node feature dim (2F)
#define NG (NN / BBG)     // 256 nodes per graph

__device__ __forceinline__ float b2f(bf16 v) { return __bfloat162float(v); }
__device__ __forceinline__ bf16 f2b(float v) { return __float2bfloat16(v); }
__device__ __forceinline__ float sb2f(short s) {
    unsigned u = ((unsigned)(unsigned short)s) << 16;
    return __builtin_bit_cast(float, u);
}
__device__ __forceinline__ short f2bs(float v) {
    bf16 b = f2b(v);
    return __builtin_bit_cast(short, b);
}
__device__ __forceinline__ int clampi(int v, int lo, int hi)
{
    return v < lo ? lo : (v > hi ? hi : v);
}

// ---- OCP e4m3fn encode/decode (manual, self-contained) ----
__device__ __forceinline__ unsigned char enc_e4m3(float y)
{
    unsigned b = __builtin_bit_cast(unsigned, y);
    unsigned s = (b >> 31) << 7;
    float a = fabsf(y);
    unsigned ab = b & 0x7fffffffu;
    unsigned rb = ab + (1u << 19);            // round half-up at mantissa bit 20
    int e = (int)(rb >> 23) - 120;
    unsigned m = (rb >> 20) & 7u;
    unsigned qn = (unsigned)(e << 3) | m;
    if (qn > 126u) qn = 126u;                 // clamp to 448, never NaN encoding
    unsigned qd = (unsigned)__float2int_rn(a * 512.f);  // denormal (rolls into 2^-6)
    unsigned q = (a < 0.015625f) ? qd : qn;
    return (unsigned char)(q | s);
}
__device__ __forceinline__ float dec_e4m3(unsigned q)
{
    unsigned e = (q >> 3) & 15u, m = q & 7u;
    float nrm = __builtin_bit_cast(float, ((e + 120u) << 23) | (m << 20));
    float dnm = (float)m * 0.001953125f;      // m * 2^-9
    float v = e ? nrm : dnm;
    return (q & 128u) ? -v : v;
}

typedef __attribute__((ext_vector_type(8))) short bf16x8;  // 8 bf16 = 4 VGPRs
typedef __attribute__((ext_vector_type(4))) float f32x4;

#define AS1 __attribute__((address_space(1)))
#define AS3 __attribute__((address_space(3)))

// ---------------------------------------------------------------------------
// MFMA bf16 GEMM: C = act(A @ Bt^T + bias). Used for x_trans.
// ---------------------------------------------------------------------------
__global__ __launch_bounds__(256) void gemm_mfma_bt(
    const bf16* __restrict__ A, const bf16* __restrict__ Bt,
    const float* __restrict__ bias, bf16* __restrict__ Cb,
    int M, int N, int K, float slope, int has_act)
{
    __shared__ bf16 As[128 * 32];
    __shared__ bf16 Bs[128 * 32];
    const int tid = threadIdx.x;
    const int w = tid >> 6;
    const int l = tid & 63;
    const int bm = blockIdx.y * 128;
    const int bn = blockIdx.x * 128;
    const int wrow = (w >> 1) * 64;
    const int wcol = (w & 1) * 64;
    const int quad = l >> 4;
    const int c16 = l & 15;

    const int lrow = l >> 2;
    const int lchunk = l & 3;
    const bf16* Ag = A + (size_t)(bm + w * 16 + lrow) * K + lchunk * 8;
    const bf16* Bg = Bt + (size_t)(bn + w * 16 + lrow) * K + lchunk * 8;
    char* AsB = (char*)As;
    char* BsB = (char*)Bs;

    f32x4 acc[4][4] = {};

    for (int k0 = 0; k0 < K; k0 += 32) {
        __builtin_amdgcn_global_load_lds((const AS1 void*)(Ag + k0),
            (AS3 void*)(AsB + w * 1024), 16, 0, 0);
        __builtin_amdgcn_global_load_lds((const AS1 void*)(Ag + (size_t)64 * K + k0),
            (AS3 void*)(AsB + 4096 + w * 1024), 16, 0, 0);
        __builtin_amdgcn_global_load_lds((const AS1 void*)(Bg + k0),
            (AS3 void*)(BsB + w * 1024), 16, 0, 0);
        __builtin_amdgcn_global_load_lds((const AS1 void*)(Bg + (size_t)64 * K + k0),
            (AS3 void*)(BsB + 4096 + w * 1024), 16, 0, 0);
        __syncthreads();

        bf16x8 a[4], b[4];
#pragma unroll
        for (int i = 0; i < 4; i++) {
            int ra = wrow + i * 16 + c16;
            a[i] = *(const bf16x8*)(AsB + ra * 64 + quad * 16);
            int rb = wcol + i * 16 + c16;
            b[i] = *(const bf16x8*)(BsB + rb * 64 + quad * 16);
        }
#pragma unroll
        for (int i = 0; i < 4; i++)
#pragma unroll
            for (int j = 0; j < 4; j++)
                acc[i][j] = __builtin_amdgcn_mfma_f32_16x16x32_bf16(
                    a[i], b[j], acc[i][j], 0, 0, 0);
        __syncthreads();
    }

#pragma unroll
    for (int i = 0; i < 4; i++) {
#pragma unroll
        for (int j = 0; j < 4; j++) {
            int col = bn + wcol + j * 16 + c16;
            float bv = bias ? bias[col] : 0.f;
#pragma unroll
            for (int r = 0; r < 4; r++) {
                int row = bm + wrow + i * 16 + quad * 4 + r;
                float v = acc[i][j][r] + bv;
                if (has_act) v = (v >= 0.f) ? v : v * slope;
                Cb[(size_t)row * N + col] = f2b(v);
            }
        }
    }
}

// ---------------------------------------------------------------------------
// Merged dual GEMM: Bt = [wlT; wrT]. cols [0,HC) -> xl, [HC,2HC) -> xr (bf16).
// quant!=0: xl half emitted as fp8-e4m3 rows (X0q) + per-16ch bf16 scales
// (X0s) computed in-epilogue (chunk == the 16 cols one quad holds).
// ---------------------------------------------------------------------------
__global__ __launch_bounds__(256) void gemm_mfma_dual(
    const bf16* __restrict__ A, const bf16* __restrict__ Bt,
    bf16* __restrict__ X0b, unsigned char* __restrict__ X0q,
    bf16* __restrict__ X0s, bf16* __restrict__ X1,
    int M, int K, int HC, int quant)
{
    __shared__ bf16 As[128 * 32];
    __shared__ bf16 Bs[128 * 32];
    const int tid = threadIdx.x;
    const int w = tid >> 6;
    const int l = tid & 63;
    const int bm = blockIdx.y * 128;
    const int bn = blockIdx.x * 128;
    const int wrow = (w >> 1) * 64;
    const int wcol = (w & 1) * 64;
    const int quad = l >> 4;
    const int c16 = l & 15;

    const int lrow = l >> 2;
    const int lchunk = l & 3;
    const bf16* Ag = A + (size_t)(bm + w * 16 + lrow) * K + lchunk * 8;
    const bf16* Bg = Bt + (size_t)(bn + w * 16 + lrow) * K + lchunk * 8;
    char* AsB = (char*)As;
    char* BsB = (char*)Bs;

    f32x4 acc[4][4] = {};

    for (int k0 = 0; k0 < K; k0 += 32) {
        __builtin_amdgcn_global_load_lds((const AS1 void*)(Ag + k0),
            (AS3 void*)(AsB + w * 1024), 16, 0, 0);
        __builtin_amdgcn_global_load_lds((const AS1 void*)(Ag + (size_t)64 * K + k0),
            (AS3 void*)(AsB + 4096 + w * 1024), 16, 0, 0);
        __builtin_amdgcn_global_load_lds((const AS1 void*)(Bg + k0),
            (AS3 void*)(BsB + w * 1024), 16, 0, 0);
        __builtin_amdgcn_global_load_lds((const AS1 void*)(Bg + (size_t)64 * K + k0),
            (AS3 void*)(BsB + 4096 + w * 1024), 16, 0, 0);
        __syncthreads();

        bf16x8 a[4], b[4];
#pragma unroll
        for (int i = 0; i < 4; i++) {
            int ra = wrow + i * 16 + c16;
            a[i] = *(const bf16x8*)(AsB + ra * 64 + quad * 16);
            int rb = wcol + i * 16 + c16;
            b[i] = *(const bf16x8*)(BsB + rb * 64 + quad * 16);
        }
#pragma unroll
        for (int i = 0; i < 4; i++)
#pragma unroll
            for (int j = 0; j < 4; j++)
                acc[i][j] = __builtin_amdgcn_mfma_f32_16x16x32_bf16(
                    a[i], b[j], acc[i][j], 0, 0, 0);
        __syncthreads();
    }

#pragma unroll
    for (int i = 0; i < 4; i++) {
#pragma unroll
        for (int j = 0; j < 4; j++) {
            int col = bn + wcol + j * 16 + c16;   // all 64 lanes same side of HC
            if (col < HC) {
                if (quant) {
#pragma unroll
                    for (int r = 0; r < 4; r++) {
                        int row = bm + wrow + i * 16 + quad * 4 + r;
                        float v = acc[i][j][r];
                        float mx = fabsf(v);
#pragma unroll
                        for (int msk = 8; msk; msk >>= 1)
                            mx = fmaxf(mx, __shfl_xor(mx, msk));
                        float sc = b2f(f2b(fmaxf(mx, 1e-20f) * (1.f / 448.f)));
                        unsigned char q = enc_e4m3(v * (1.f / sc));
                        X0q[(size_t)row * HC + col] = q;
                        if (c16 == 0)
                            X0s[(size_t)row * (HC / 16) + (col >> 4)] = f2b(sc);
                    }
                } else {
#pragma unroll
                    for (int r = 0; r < 4; r++) {
                        int row = bm + wrow + i * 16 + quad * 4 + r;
                        X0b[(size_t)row * HC + col] = f2b(acc[i][j][r]);
                    }
                }
            } else {
#pragma unroll
                for (int r = 0; r < 4; r++) {
                    int row = bm + wrow + i * 16 + quad * 4 + r;
                    X1[(size_t)row * HC + col - HC] = f2b(acc[i][j][r]);
                }
            }
        }
    }
}

// ---------------------------------------------------------------------------
// fp32 GEMM (head MLP only)
// ---------------------------------------------------------------------------
__global__ __launch_bounds__(256) void gemm_f32(
    const float* __restrict__ A, const float* __restrict__ W,
    const float* __restrict__ bias, float* __restrict__ C,
    int M, int N, int K, float slope, int has_act)
{
    const int BK = 16;
    __shared__ float Asm[BK][64 + 1];
    __shared__ float Wsm[BK][64 + 1];
    int tid = threadIdx.x;
    int bm = blockIdx.y * 64;
    int bn = blockIdx.x * 64;
    int tr = tid >> 4;
    int tc = tid & 15;
    float acc[4][4] = {};

    for (int k0 = 0; k0 < K; k0 += BK) {
        {
            int col = tid & 15;
            int row = tid >> 4;
#pragma unroll
            for (int p = 0; p < 4; p++) {
                int r = row + p * 16;
                Asm[col][r] = A[(size_t)(bm + r) * K + k0 + col];
            }
        }
        {
            int wc = tid & 63;
            int wr = tid >> 6;
#pragma unroll
            for (int p = 0; p < 4; p++) {
                int r = wr + p * 4;
                Wsm[r][wc] = W[(size_t)(k0 + r) * N + bn + wc];
            }
        }
        __syncthreads();
#pragma unroll
        for (int kk = 0; kk < BK; kk++) {
            float a[4], w[4];
#pragma unroll
            for (int i = 0; i < 4; i++) a[i] = Asm[kk][tr * 4 + i];
#pragma unroll
            for (int j = 0; j < 4; j++) w[j] = Wsm[kk][tc * 4 + j];
#pragma unroll
            for (int i = 0; i < 4; i++)
#pragma unroll
                for (int j = 0; j < 4; j++)
                    acc[i][j] += a[i] * w[j];
        }
        __syncthreads();
    }
#pragma unroll
    for (int i = 0; i < 4; i++) {
        int r = bm + tr * 4 + i;
#pragma unroll
        for (int j = 0; j < 4; j++) {
            int cn = bn + tc * 4 + j;
            float v = acc[i][j];
            if (bias) v += bias[cn];
            if (has_act) v = (v >= 0.f) ? v : v * slope;
            C[(size_t)r * N + cn] = v;
        }
    }
}

// ---------------------------------------------------------------------------
// Batched fp32 [R,C] -> bf16 [C,R] transpose-convert, 12 slices in one launch
// ---------------------------------------------------------------------------
struct TPackAll {
    const float* in[12];
    bf16* out[12];
    int R[12], C[12];
};

__global__ __launch_bounds__(256) void transpose_batch(TPackAll pk)
{
    int z = blockIdx.z;
    int R = pk.R[z], C = pk.C[z];
    int c0 = blockIdx.x * 32;
    int r0 = blockIdx.y * 32;
    if (c0 >= C || r0 >= R) return;
    const float* in = pk.in[z];
    bf16* out = pk.out[z];
    __shared__ float tile[32][33];
    int tx = threadIdx.x & 31;
    int ty = threadIdx.x >> 5;
#pragma unroll
    for (int k = 0; k < 4; k++) {
        int r = ty + k * 8;
        tile[r][tx] = in[(size_t)(r0 + r) * C + c0 + tx];
    }
    __syncthreads();
#pragma unroll
    for (int k = 0; k < 4; k++) {
        int rr = ty + k * 8;
        out[(size_t)(c0 + rr) * R + r0 + tx] = f2b(tile[tx][rr]);
    }
}

__global__ void f2b_vec(const float* __restrict__ in, bf16* __restrict__ out, int n)
{
    int i = blockIdx.x * 256 + threadIdx.x;
    if (i < n) out[i] = f2b(in[i]);
}

// ---------------------------------------------------------------------------
// CSR build over dst (self loops: edge ids [EE, ET) are node e-EE)
// ---------------------------------------------------------------------------
__global__ void count_deg(const int* __restrict__ ei, int* __restrict__ deg)
{
    int e = blockIdx.x * 256 + threadIdx.x;
    if (e >= ET) return;
    int d = (e < EE) ? ei[EE + e] : (e - EE);
    d = clampi(d, 0, NN - 1);
    atomicAdd(&deg[d], 1);
}

__global__ __launch_bounds__(256) void scan_deg(const int* __restrict__ deg,
                                                int* __restrict__ rs)
{
    __shared__ int part[256];
    __shared__ int psum[257];
    int tid = threadIdx.x;
    const int per = NN / 256;
    int base = tid * per;
    int s = 0;
    for (int i = 0; i < per; i++) s += deg[base + i];
    part[tid] = s;
    __syncthreads();
    if (tid == 0) {
        int acc = 0;
        for (int i = 0; i < 256; i++) { psum[i] = acc; acc += part[i]; }
        psum[256] = acc;
    }
    __syncthreads();
    int acc = psum[tid];
    for (int i = 0; i < per; i++) { rs[base + i] = acc; acc += deg[base + i]; }
    if (tid == 0) rs[NN] = psum[256];
}

__global__ void fill_csr(const int* __restrict__ ei, const int* __restrict__ rs,
                         int* __restrict__ cur, int* __restrict__ csrc)
{
    int e = blockIdx.x * 256 + threadIdx.x;
    if (e >= ET) return;
    int s, d;
    if (e < EE) { s = ei[e]; d = ei[EE + e]; } else { s = d = e - EE; }
    s = clampi(s, 0, NN - 1);
    d = clampi(d, 0, NN - 1);
    int pos = atomicAdd(&cur[d], 1);
    int slot = clampi(rs[d] + pos, 0, ET - 1);
    csrc[slot] = s;
}

// ---------------------------------------------------------------------------
// GATv2 edge phase, fp8-gather variant (HC=1024, heads=2). Wave-per-node,
// R6 rotation depth-3 prefetch, online softmax. Rows: 16 fp8 + 1 bf16 scale
// per lane (vs 32B bf16) — halves the fabric-bound gather traffic.
// ---------------------------------------------------------------------------
__global__ __launch_bounds__(256, 4) void gat_q(
    const unsigned char* __restrict__ xlq, const bf16* __restrict__ xls,
    const bf16* __restrict__ xr, const float* __restrict__ att,
    const float* __restrict__ bias, const int* __restrict__ rs,
    const int* __restrict__ csrc, bf16* __restrict__ out_b)
{
    constexpr int HC = 1024, CPL = 16;
    const int tid = threadIdx.x;
    const int w = tid >> 6;
    const int lane = tid & 63;
    const int n = blockIdx.x * 4 + w;
    const int c0 = lane * CPL;

    int start = rs[n];
    int deg = clampi(rs[n + 1] - start, 1, 64);
    start = clampi(start, 0, ET - 1);
    int my_src = 0;
    if (lane < deg) my_src = clampi(csrc[start + lane], 0, NN - 1);

    float av[CPL], rv[CPL];
    {
        bf16x8 r0 = *(const bf16x8*)(xr + (size_t)n * HC + c0);
        bf16x8 r1 = *(const bf16x8*)(xr + (size_t)n * HC + c0 + 8);
#pragma unroll
        for (int k = 0; k < 8; k++) { rv[k] = sb2f(r0[k]); rv[8 + k] = sb2f(r1[k]); }
#pragma unroll
        for (int k = 0; k < CPL; k++) av[k] = att[c0 + k];
    }

    float m = -1e30f, den = 0.f;
    float acc[CPL];
#pragma unroll
    for (int k = 0; k < CPL; k++) acc[k] = 0.f;

    auto loadrow = [&](int i, uint4& q, float& sc) {
        int s = __shfl(my_src, i);
        q = *(const uint4*)(xlq + (size_t)s * HC + c0);
        sc = b2f(xls[(size_t)s * 64 + lane]);
    };
    auto process = [&](const uint4& q, float sc) {
        float x[CPL];
        const unsigned* qw = (const unsigned*)&q;
#pragma unroll
        for (int k = 0; k < CPL; k++)
            x[k] = dec_e4m3((qw[k >> 2] >> ((k & 3) * 8)) & 255u) * sc;
        float part = 0.f;
#pragma unroll
        for (int k = 0; k < CPL; k++) {
            float u = x[k] + rv[k];
            u = (u >= 0.f) ? u : 0.2f * u;
            part = fmaf(av[k], u, part);
        }
#pragma unroll
        for (int msk = 16; msk; msk >>= 1) part += __shfl_xor(part, msk);
        float lg = part;
        float mn = fmaxf(m, lg);
        float r = __expf(m - mn);
        float pi = __expf(lg - mn);
        m = mn;
        den = den * r + pi;
#pragma unroll
        for (int k = 0; k < CPL; k++) acc[k] = fmaf(acc[k], r, pi * x[k]);
    };

    uint4 cq, q1, q2, qn;
    float cs, s1, s2, sn;
    loadrow(0, cq, cs);
    if (deg > 1) loadrow(1, q1, s1);
    if (deg > 2) loadrow(2, q2, s2);
    for (int i = 0; i < deg; i++) {
        if (i + 3 < deg) loadrow(i + 3, qn, sn);
        process(cq, cs);
        cq = q1; cs = s1; q1 = q2; s1 = s2; q2 = qn; s2 = sn;
    }

    float inv = 1.f / den;
    bf16x8 ov0, ov1;
#pragma unroll
    for (int k = 0; k < 8; k++) {
        float v = fmaf(acc[k], inv, bias[c0 + k]);
        v = (v >= 0.f) ? v : 0.01f * v;
        ov0[k] = f2bs(v);
        float v2 = fmaf(acc[8 + k], inv, bias[c0 + 8 + k]);
        v2 = (v2 >= 0.f) ? v2 : 0.01f * v2;
        ov1[k] = f2bs(v2);
    }
    *(bf16x8*)(out_b + (size_t)n * HC + c0) = ov0;
    *(bf16x8*)(out_b + (size_t)n * HC + c0 + 8) = ov1;
}

// ---------------------------------------------------------------------------
// GATv2 edge phase, bf16-gather variant (L3: HC=1024; L4: HC=512 + residual
// + LN sums). Exact R6 structure (best measured).
// ---------------------------------------------------------------------------
template<int HC>
__global__ __launch_bounds__(256) void gat_b(
    const bf16* __restrict__ xl, const bf16* __restrict__ xr,
    const float* __restrict__ att, const float* __restrict__ bias,
    const int* __restrict__ rs, const int* __restrict__ csrc,
    const bf16* __restrict__ res, bf16* __restrict__ out_b,
    float* __restrict__ lnsums)
{
    constexpr int CPL = HC / 64;
    constexpr int NV = CPL / 8;
    const int tid = threadIdx.x;
    const int w = tid >> 6;
    const int lane = tid & 63;
    const int n = blockIdx.x * 4 + w;
    const int c0 = lane * CPL;

    int start = rs[n];
    int deg = clampi(rs[n + 1] - start, 1, 64);
    start = clampi(start, 0, ET - 1);
    int my_src = 0;
    if (lane < deg) my_src = clampi(csrc[start + lane], 0, NN - 1);

    float av[CPL], rv[CPL];
    {
        bf16x8 rp[NV];
#pragma unroll
        for (int v = 0; v < NV; v++)
            rp[v] = *(const bf16x8*)(xr + (size_t)n * HC + c0 + v * 8);
#pragma unroll
        for (int k = 0; k < CPL; k++) {
            rv[k] = sb2f(rp[k / 8][k % 8]);
            av[k] = att[c0 + k];
        }
    }

    float m = -1e30f, den = 0.f;
    float acc[CPL];
#pragma unroll
    for (int k = 0; k < CPL; k++) acc[k] = 0.f;

    auto loadrow = [&](int i, bf16x8* dst) {
        int s = __shfl(my_src, i);
        const bf16* rp = xl + (size_t)s * HC + c0;
#pragma unroll
        for (int v = 0; v < NV; v++) dst[v] = *(const bf16x8*)(rp + v * 8);
    };

    bf16x8 cur[NV], nx1[NV], nx2[NV];
    loadrow(0, cur);
    if (deg > 1) loadrow(1, nx1);
    if (deg > 2) loadrow(2, nx2);

    for (int i = 0; i < deg; i++) {
        bf16x8 nxt[NV];
        if (i + 3 < deg) loadrow(i + 3, nxt);

        float part = 0.f;
#pragma unroll
        for (int k = 0; k < CPL; k++) {
            float x = sb2f(cur[k / 8][k % 8]);
            float u = x + rv[k];
            u = (u >= 0.f) ? u : 0.2f * u;
            part = fmaf(av[k], u, part);
        }
        if (HC == 1024) {
#pragma unroll
            for (int msk = 16; msk; msk >>= 1) part += __shfl_xor(part, msk);
        } else {
#pragma unroll
            for (int msk = 32; msk; msk >>= 1) part += __shfl_xor(part, msk);
        }
        float lg = part;
        float mn = fmaxf(m, lg);
        float r = __expf(m - mn);
        float pi = __expf(lg - mn);
        m = mn;
        den = den * r + pi;
#pragma unroll
        for (int k = 0; k < CPL; k++) {
            float x = sb2f(cur[k / 8][k % 8]);
            acc[k] = fmaf(acc[k], r, pi * x);
        }
#pragma unroll
        for (int v = 0; v < NV; v++) { cur[v] = nx1[v]; nx1[v] = nx2[v]; nx2[v] = nxt[v]; }
    }

    float inv = 1.f / den;
    float ls = 0.f, ls2 = 0.f;
    float vals[CPL];
#pragma unroll
    for (int k = 0; k < CPL; k++) {
        float v = fmaf(acc[k], inv, bias[c0 + k]);
        v = (v >= 0.f) ? v : 0.01f * v;
        vals[k] = v;
    }
    if (res) {
        bf16x8 rr[NV];
#pragma unroll
        for (int v = 0; v < NV; v++)
            rr[v] = *(const bf16x8*)(res + (size_t)n * HC + c0 + v * 8);
#pragma unroll
        for (int k = 0; k < CPL; k++) {
            vals[k] += sb2f(rr[k / 8][k % 8]);
            ls += vals[k];
            ls2 += vals[k] * vals[k];
        }
    }
#pragma unroll
    for (int v = 0; v < NV; v++) {
        bf16x8 ov;
#pragma unroll
        for (int k = 0; k < 8; k++) ov[k] = f2bs(vals[v * 8 + k]);
        *(bf16x8*)(out_b + (size_t)n * HC + c0 + v * 8) = ov;
    }

    if (lnsums) {
#pragma unroll
        for (int msk = 32; msk; msk >>= 1) {
            ls += __shfl_xor(ls, msk);
            ls2 += __shfl_xor(ls2, msk);
        }
        if (lane == 0) {
            int g = n >> 8;
            atomicAdd(&lnsums[g], ls);
            atomicAdd(&lnsums[BBG + g], ls2);
        }
    }
}

// ---------------------------------------------------------------------------
// LN apply + channel-wise online-softmax aggregation (bf16 h), partials.
// ---------------------------------------------------------------------------
__global__ __launch_bounds__(256) void aggr_partial(
    const bf16* __restrict__ h, const float* __restrict__ lnsums,
    const float* __restrict__ lnw, const float* __restrict__ lnb,
    const float* __restrict__ t_, float* __restrict__ pm,
    float* __restrict__ pd, float* __restrict__ pa)
{
    int g = blockIdx.x, ch = blockIdx.y, nk = blockIdx.z;
    int tid = threadIdx.x;
    int c = ch * 256 + tid;
    const float tot = (float)(NG * DD);
    float S = lnsums[g], S2 = lnsums[BBG + g];
    float mu = S / tot;
    float iv = rsqrtf(fmaxf(S2 / tot - mu * mu, 0.f) + 1e-5f);
    float w = lnw[c], b = lnb[c], t = t_[0];
    size_t base = (size_t)g * NG * DD + (size_t)nk * 32 * DD + c;
    float m = -1e30f, den = 0.f, acc = 0.f;
    for (int i = 0; i < 32; i++) {
        float hn = (b2f(h[base + (size_t)i * DD]) - mu) * iv * w + b;
        float lg = hn * t;
        if (lg > m) {
            float r = __expf(m - lg);
            den *= r; acc *= r; m = lg;
        }
        float p = __expf(lg - m);
        den += p; acc += p * hn;
    }
    size_t idx = (((size_t)g * 2 + ch) * 8 + nk) * 256 + tid;
    pm[idx] = m; pd[idx] = den; pa[idx] = acc;
}

__global__ __launch_bounds__(256) void aggr_combine(
    const float* __restrict__ pm, const float* __restrict__ pd,
    const float* __restrict__ pa, float* __restrict__ gout)
{
    int g = blockIdx.x, ch = blockIdx.y;
    int tid = threadIdx.x;
    size_t base = (((size_t)g * 2 + ch) * 8) * 256 + tid;
    float m = -1e30f;
#pragma unroll
    for (int k = 0; k < 8; k++) m = fmaxf(m, pm[base + k * 256]);
    float den = 0.f, acc = 0.f;
#pragma unroll
    for (int k = 0; k < 8; k++) {
        float r = __expf(pm[base + k * 256] - m);
        den += pd[base + k * 256] * r;
        acc += pa[base + k * 256] * r;
    }
    gout[(size_t)g * DD + ch * 256 + tid] = acc / den;
}

// ---------------------------------------------------------------------------
extern "C" void kernel_launch(void* const* d_in, const int* in_sizes, int n_in,
                              void* d_out, int out_size, void* d_ws, size_t ws_size,
                              hipStream_t stream)
{
    const float* x      = (const float*)d_in[0];
    const int*   ei     = (const int*)d_in[1];
    const float* xt_w1  = (const float*)d_in[3];
    const float* xt_b1  = (const float*)d_in[4];
    const float* xt_w2  = (const float*)d_in[5];
    const float* xt_b2  = (const float*)d_in[6];
    const float* ln_w   = (const float*)d_in[27];
    const float* ln_b   = (const float*)d_in[28];
    const float* aggr_t = (const float*)d_in[29];
    const float* m_w1   = (const float*)d_in[30];
    const float* m_b1   = (const float*)d_in[31];
    const float* m_w2   = (const float*)d_in[32];
    const float* m_b2   = (const float*)d_in[33];
    const float* m_w3   = (const float*)d_in[34];
    const float* m_b3   = (const float*)d_in[35];
    float* out = (float*)d_out;

    // ---- workspace layout (256B aligned); ints first ----
    char* p = (char*)d_ws;
    auto take = [&](size_t bytes) {
        char* r = p;
        p += (bytes + 255) & ~(size_t)255;
        return r;
    };
    int* i_deg     = (int*)take((size_t)(NN + 1) * 4);
    int* i_rs      = (int*)take((size_t)(NN + 1) * 4);
    int* i_cur     = (int*)take((size_t)NN * 4);
    int* i_src     = (int*)take((size_t)ET * 4);
    float* f_sums  = (float*)take((size_t)2 * BBG * 4);
    float* f_pm    = (float*)take((size_t)BBG * 2 * 8 * 256 * 4);
    float* f_pd    = (float*)take((size_t)BBG * 2 * 8 * 256 * 4);
    float* f_pa    = (float*)take((size_t)BBG * 2 * 8 * 256 * 4);
    float* b_g     = (float*)take((size_t)BBG * DD * 4);
    float* b_m1    = (float*)take((size_t)BBG * 384 * 4);
    float* b_m2    = (float*)take((size_t)BBG * 256 * 4);
    bf16* b_resb   = (bf16*)take((size_t)NN * DD * 2);       // bf16 cx/residual
    bf16* b_h      = (bf16*)take((size_t)NN * DD * 2);       // bf16 final h (L4)
    bf16* b_hb     = (bf16*)take((size_t)NN * 1024 * 2);     // bf16 h (alias t1b)
    bf16* b_xlb    = (bf16*)take((size_t)NN * 1024 * 2);     // bf16 xl (L3 only)
    bf16* b_xrb    = (bf16*)take((size_t)NN * 1024 * 2);     // bf16 xr
    unsigned char* b_xlq = (unsigned char*)take((size_t)NN * 1024); // fp8 xl
    bf16* b_xls    = (bf16*)take((size_t)NN * 64 * 2);       // per-16ch scales
    bf16* b_xb     = (bf16*)take((size_t)2 * NN * 32 * 2);
    bf16* b_wcat   = (bf16*)take((size_t)8 * 1024 * 1024 * 2); // all [wlT;wrT]
    bf16* b_w1b    = (bf16*)take((size_t)32 * 256 * 2);
    bf16* b_w2b    = (bf16*)take((size_t)256 * 256 * 2);
    bf16* b_t1b = b_hb;

    // wcat element offsets per layer
    size_t woff[5], wlen[5];
    {
        size_t o = 0;
        for (int L = 0; L < 5; L++) {
            int Fin = (L == 0) ? 512 : 1024;
            int HC  = (L == 4) ? 512 : 1024;
            woff[L] = o;
            wlen[L] = (size_t)2 * HC * Fin;
            o += wlen[L];
        }
    }

    dim3 blk(256);

    // ---- CSR build + LN-sum zero ----
    hipMemsetAsync(i_deg, 0, (size_t)(NN + 1) * 4, stream);
    hipMemsetAsync(i_cur, 0, (size_t)NN * 4, stream);
    hipMemsetAsync(f_sums, 0, (size_t)2 * BBG * 4, stream);
    count_deg<<<ET / 256, blk, 0, stream>>>(ei, i_deg);
    scan_deg<<<1, blk, 0, stream>>>(i_deg, i_rs);
    fill_csr<<<ET / 256, blk, 0, stream>>>(ei, i_rs, i_cur, i_src);

    // ---- x convert + ALL weight transposes in one launch ----
    f2b_vec<<<(2 * NN * 32 + 255) / 256, blk, 0, stream>>>(x, b_xb, 2 * NN * 32);
    {
        TPackAll pk;
        pk.in[0] = xt_w1; pk.out[0] = b_w1b; pk.R[0] = 32;  pk.C[0] = 256;
        pk.in[1] = xt_w2; pk.out[1] = b_w2b; pk.R[1] = 256; pk.C[1] = 256;
        for (int L = 0; L < 5; L++) {
            int Fin = (L == 0) ? 512 : 1024;
            int HC  = (L == 4) ? 512 : 1024;
            pk.in[2 + 2 * L] = (const float*)d_in[7 + 4 * L];      // wl
            pk.out[2 + 2 * L] = b_wcat + woff[L];
            pk.R[2 + 2 * L] = Fin; pk.C[2 + 2 * L] = HC;
            pk.in[3 + 2 * L] = (const float*)d_in[8 + 4 * L];      // wr
            pk.out[3 + 2 * L] = b_wcat + woff[L] + (size_t)HC * Fin;
            pk.R[3 + 2 * L] = Fin; pk.C[3 + 2 * L] = HC;
        }
        transpose_batch<<<dim3(32, 32, 12), blk, 0, stream>>>(pk);
    }

    // ---- x_trans ----
    gemm_mfma_bt<<<dim3(256 / 128, 32768 / 128), blk, 0, stream>>>(
        b_xb, b_w1b, xt_b1, b_t1b, 32768, 256, 32, 0.01f, 1);
    gemm_mfma_bt<<<dim3(256 / 128, 32768 / 128), blk, 0, stream>>>(
        b_t1b, b_w2b, xt_b2, b_resb, 32768, 256, 256, 0.f, 0);

    // ---- 5 GATv2 layers ----
    for (int L = 0; L < 5; L++) {
        const float* att = (const float*)d_in[9 + 4 * L];
        const float* gb  = (const float*)d_in[10 + 4 * L];
        int Fin = (L == 0) ? 512 : 1024;
        int HC  = (L == 4) ? 512 : 1024;
        int quant = (L <= 2) ? 1 : 0;
        const bf16* hin = (L == 0) ? b_resb : b_hb;

        gemm_mfma_dual<<<dim3(2 * HC / 128, NN / 128), blk, 0, stream>>>(
            hin, b_wcat + woff[L],
            quant ? (bf16*)nullptr : b_xlb, b_xlq, b_xls, b_xrb,
            NN, Fin, HC, quant);
        if (L <= 2) {
            gat_q<<<NN / 4, blk, 0, stream>>>(
                b_xlq, b_xls, b_xrb, att, gb, i_rs, i_src, b_hb);
        } else if (L == 3) {
            gat_b<1024><<<NN / 4, blk, 0, stream>>>(
                b_xlb, b_xrb, att, gb, i_rs, i_src,
                (const bf16*)nullptr, b_hb, (float*)nullptr);
        } else {
            gat_b<512><<<NN / 4, blk, 0, stream>>>(
                b_xlb, b_xrb, att, gb, i_rs, i_src,
                b_resb, b_h, f_sums);
        }
    }

    // ---- graph LN + softmax aggregation ----
    aggr_partial<<<dim3(BBG, 2, 8), blk, 0, stream>>>(
        b_h, f_sums, ln_w, ln_b, aggr_t, f_pm, f_pd, f_pa);
    aggr_combine<<<dim3(BBG, 2), blk, 0, stream>>>(f_pm, f_pd, f_pa, b_g);

    // ---- head MLP 512 -> 384 -> 256 -> 128 (fp32) ----
    gemm_f32<<<dim3(384 / 64, 1), blk, 0, stream>>>(
        b_g, m_w1, m_b1, b_m1, 64, 384, 512, 0.01f, 1);
    gemm_f32<<<dim3(256 / 64, 1), blk, 0, stream>>>(
        b_m1, m_w2, m_b2, b_m2, 64, 256, 384, 0.01f, 1);
    gemm_f32<<<dim3(128 / 64, 1), blk, 0, stream>>>(
        b_m2, m_w3, m_b3, out, 64, 128, 256, 0.f, 0);
}

// Round 9
// 1085.831 us; speedup vs baseline: 1.0707x; 1.0707x over previous
//
#include <hip/hip_runtime.h>
#include <hip/hip_bf16.h>

typedef __hip_bfloat16 bf16;

#define NN 16384          // gate nodes
#define BBG 64            // graphs
#define EE 49152          // directed edges (no self loops)
#define ET (EE + NN)      // edges + self loops = 65536
#define DD 512            // node feature dim (2F)
#define NG (NN / BBG)     // 256 nodes per graph

__device__ __forceinline__ float b2f(bf16 v) { return __bfloat162float(v); }
__device__ __forceinline__ bf16 f2b(float v) { return __float2bfloat16(v); }
__device__ __forceinline__ float sb2f(short s) {
    unsigned u = ((unsigned)(unsigned short)s) << 16;
    return __builtin_bit_cast(float, u);
}
__device__ __forceinline__ short f2bs(float v) {
    bf16 b = f2b(v);
    return __builtin_bit_cast(short, b);
}
__device__ __forceinline__ int clampi(int v, int lo, int hi)
{
    return v < lo ? lo : (v > hi ? hi : v);
}

// ---- OCP e4m3fn encode/decode (manual, self-contained) ----
__device__ __forceinline__ unsigned char enc_e4m3(float y)
{
    unsigned b = __builtin_bit_cast(unsigned, y);
    unsigned s = (b >> 31) << 7;
    float a = fabsf(y);
    unsigned ab = b & 0x7fffffffu;
    unsigned rb = ab + (1u << 19);            // round half-up at mantissa bit 20
    int e = (int)(rb >> 23) - 120;
    unsigned m = (rb >> 20) & 7u;
    unsigned qn = (unsigned)(e << 3) | m;
    if (qn > 126u) qn = 126u;                 // clamp to 448, never NaN encoding
    unsigned qd = (unsigned)__float2int_rn(a * 512.f);  // denormal
    unsigned q = (a < 0.015625f) ? qd : qn;
    return (unsigned char)(q | s);
}
__device__ __forceinline__ float dec_e4m3(unsigned q)
{
    unsigned e = (q >> 3) & 15u, m = q & 7u;
    float nrm = __builtin_bit_cast(float, ((e + 120u) << 23) | (m << 20));
    float dnm = (float)m * 0.001953125f;      // m * 2^-9
    float v = e ? nrm : dnm;
    return (q & 128u) ? -v : v;
}

typedef __attribute__((ext_vector_type(8))) short bf16x8;  // 8 bf16 = 4 VGPRs
typedef __attribute__((ext_vector_type(4))) float f32x4;

#define AS1 __attribute__((address_space(1)))
#define AS3 __attribute__((address_space(3)))

// ---------------------------------------------------------------------------
// MFMA bf16 GEMM: C = act(A @ Bt^T + bias). Used for x_trans.
// ---------------------------------------------------------------------------
__global__ __launch_bounds__(256) void gemm_mfma_bt(
    const bf16* __restrict__ A, const bf16* __restrict__ Bt,
    const float* __restrict__ bias, bf16* __restrict__ Cb,
    int M, int N, int K, float slope, int has_act)
{
    __shared__ bf16 As[128 * 32];
    __shared__ bf16 Bs[128 * 32];
    const int tid = threadIdx.x;
    const int w = tid >> 6;
    const int l = tid & 63;
    const int bm = blockIdx.y * 128;
    const int bn = blockIdx.x * 128;
    const int wrow = (w >> 1) * 64;
    const int wcol = (w & 1) * 64;
    const int quad = l >> 4;
    const int c16 = l & 15;

    const int lrow = l >> 2;
    const int lchunk = l & 3;
    const bf16* Ag = A + (size_t)(bm + w * 16 + lrow) * K + lchunk * 8;
    const bf16* Bg = Bt + (size_t)(bn + w * 16 + lrow) * K + lchunk * 8;
    char* AsB = (char*)As;
    char* BsB = (char*)Bs;

    f32x4 acc[4][4] = {};

    for (int k0 = 0; k0 < K; k0 += 32) {
        __builtin_amdgcn_global_load_lds((const AS1 void*)(Ag + k0),
            (AS3 void*)(AsB + w * 1024), 16, 0, 0);
        __builtin_amdgcn_global_load_lds((const AS1 void*)(Ag + (size_t)64 * K + k0),
            (AS3 void*)(AsB + 4096 + w * 1024), 16, 0, 0);
        __builtin_amdgcn_global_load_lds((const AS1 void*)(Bg + k0),
            (AS3 void*)(BsB + w * 1024), 16, 0, 0);
        __builtin_amdgcn_global_load_lds((const AS1 void*)(Bg + (size_t)64 * K + k0),
            (AS3 void*)(BsB + 4096 + w * 1024), 16, 0, 0);
        __syncthreads();

        bf16x8 a[4], b[4];
#pragma unroll
        for (int i = 0; i < 4; i++) {
            int ra = wrow + i * 16 + c16;
            a[i] = *(const bf16x8*)(AsB + ra * 64 + quad * 16);
            int rb = wcol + i * 16 + c16;
            b[i] = *(const bf16x8*)(BsB + rb * 64 + quad * 16);
        }
#pragma unroll
        for (int i = 0; i < 4; i++)
#pragma unroll
            for (int j = 0; j < 4; j++)
                acc[i][j] = __builtin_amdgcn_mfma_f32_16x16x32_bf16(
                    a[i], b[j], acc[i][j], 0, 0, 0);
        __syncthreads();
    }

#pragma unroll
    for (int i = 0; i < 4; i++) {
#pragma unroll
        for (int j = 0; j < 4; j++) {
            int col = bn + wcol + j * 16 + c16;
            float bv = bias ? bias[col] : 0.f;
#pragma unroll
            for (int r = 0; r < 4; r++) {
                int row = bm + wrow + i * 16 + quad * 4 + r;
                float v = acc[i][j][r] + bv;
                if (has_act) v = (v >= 0.f) ? v : v * slope;
                Cb[(size_t)row * N + col] = f2b(v);
            }
        }
    }
}

// ---------------------------------------------------------------------------
// Merged dual GEMM (clean R7 epilogue): Bt = [wlT; wrT]. cols [0,HC) -> X0,
// [HC,2HC) -> X1, both bf16.
// ---------------------------------------------------------------------------
__global__ __launch_bounds__(256) void gemm_mfma_dual(
    const bf16* __restrict__ A, const bf16* __restrict__ Bt,
    bf16* __restrict__ X0, bf16* __restrict__ X1,
    int M, int K, int HC)
{
    __shared__ bf16 As[128 * 32];
    __shared__ bf16 Bs[128 * 32];
    const int tid = threadIdx.x;
    const int w = tid >> 6;
    const int l = tid & 63;
    const int bm = blockIdx.y * 128;
    const int bn = blockIdx.x * 128;
    const int wrow = (w >> 1) * 64;
    const int wcol = (w & 1) * 64;
    const int quad = l >> 4;
    const int c16 = l & 15;

    const int lrow = l >> 2;
    const int lchunk = l & 3;
    const bf16* Ag = A + (size_t)(bm + w * 16 + lrow) * K + lchunk * 8;
    const bf16* Bg = Bt + (size_t)(bn + w * 16 + lrow) * K + lchunk * 8;
    char* AsB = (char*)As;
    char* BsB = (char*)Bs;

    f32x4 acc[4][4] = {};

    for (int k0 = 0; k0 < K; k0 += 32) {
        __builtin_amdgcn_global_load_lds((const AS1 void*)(Ag + k0),
            (AS3 void*)(AsB + w * 1024), 16, 0, 0);
        __builtin_amdgcn_global_load_lds((const AS1 void*)(Ag + (size_t)64 * K + k0),
            (AS3 void*)(AsB + 4096 + w * 1024), 16, 0, 0);
        __builtin_amdgcn_global_load_lds((const AS1 void*)(Bg + k0),
            (AS3 void*)(BsB + w * 1024), 16, 0, 0);
        __builtin_amdgcn_global_load_lds((const AS1 void*)(Bg + (size_t)64 * K + k0),
            (AS3 void*)(BsB + 4096 + w * 1024), 16, 0, 0);
        __syncthreads();

        bf16x8 a[4], b[4];
#pragma unroll
        for (int i = 0; i < 4; i++) {
            int ra = wrow + i * 16 + c16;
            a[i] = *(const bf16x8*)(AsB + ra * 64 + quad * 16);
            int rb = wcol + i * 16 + c16;
            b[i] = *(const bf16x8*)(BsB + rb * 64 + quad * 16);
        }
#pragma unroll
        for (int i = 0; i < 4; i++)
#pragma unroll
            for (int j = 0; j < 4; j++)
                acc[i][j] = __builtin_amdgcn_mfma_f32_16x16x32_bf16(
                    a[i], b[j], acc[i][j], 0, 0, 0);
        __syncthreads();
    }

#pragma unroll
    for (int i = 0; i < 4; i++) {
#pragma unroll
        for (int j = 0; j < 4; j++) {
            int col = bn + wcol + j * 16 + c16;
            bf16* dst = (col < HC) ? (X0 + col) : (X1 + col - HC);
#pragma unroll
            for (int r = 0; r < 4; r++) {
                int row = bm + wrow + i * 16 + quad * 4 + r;
                dst[(size_t)row * HC] = f2b(acc[i][j][r]);
            }
        }
    }
}

// ---------------------------------------------------------------------------
// Row quantizer: bf16 [NN,1024] -> fp8 e4m3 [NN,1024] + per-16ch bf16 scales
// [NN,64]. One wave per node; lane k owns channels [16k,16k+16) -> the
// group max is PURELY IN-LANE (zero shuffles; this is what the R8 epilogue
// got wrong). Coalesced bf16x8 reads, uint4 + scalar writes.
// ---------------------------------------------------------------------------
__global__ __launch_bounds__(256, 4) void quant_rows(
    const bf16* __restrict__ xl, unsigned char* __restrict__ xq,
    bf16* __restrict__ xs)
{
    const int n = blockIdx.x * 4 + (threadIdx.x >> 6);
    const int lane = threadIdx.x & 63;
    const bf16* rp = xl + (size_t)n * 1024 + lane * 16;
    bf16x8 v0 = *(const bf16x8*)(rp);
    bf16x8 v1 = *(const bf16x8*)(rp + 8);
    float x[16];
#pragma unroll
    for (int k = 0; k < 8; k++) { x[k] = sb2f(v0[k]); x[8 + k] = sb2f(v1[k]); }
    float mx = 0.f;
#pragma unroll
    for (int k = 0; k < 16; k++) mx = fmaxf(mx, fabsf(x[k]));
    float sc = b2f(f2b(fmaxf(mx, 1e-20f) * (1.f / 448.f)));
    float isc = 1.f / sc;
    uint4 q;
    unsigned* qw = (unsigned*)&q;
#pragma unroll
    for (int w = 0; w < 4; w++) {
        unsigned pk = 0;
#pragma unroll
        for (int b = 0; b < 4; b++)
            pk |= ((unsigned)enc_e4m3(x[w * 4 + b] * isc)) << (b * 8);
        qw[w] = pk;
    }
    *(uint4*)(xq + (size_t)n * 1024 + lane * 16) = q;
    xs[(size_t)n * 64 + lane] = f2b(sc);
}

// ---------------------------------------------------------------------------
// fp32 GEMM (head MLP only)
// ---------------------------------------------------------------------------
__global__ __launch_bounds__(256) void gemm_f32(
    const float* __restrict__ A, const float* __restrict__ W,
    const float* __restrict__ bias, float* __restrict__ C,
    int M, int N, int K, float slope, int has_act)
{
    const int BK = 16;
    __shared__ float Asm[BK][64 + 1];
    __shared__ float Wsm[BK][64 + 1];
    int tid = threadIdx.x;
    int bm = blockIdx.y * 64;
    int bn = blockIdx.x * 64;
    int tr = tid >> 4;
    int tc = tid & 15;
    float acc[4][4] = {};

    for (int k0 = 0; k0 < K; k0 += BK) {
        {
            int col = tid & 15;
            int row = tid >> 4;
#pragma unroll
            for (int p = 0; p < 4; p++) {
                int r = row + p * 16;
                Asm[col][r] = A[(size_t)(bm + r) * K + k0 + col];
            }
        }
        {
            int wc = tid & 63;
            int wr = tid >> 6;
#pragma unroll
            for (int p = 0; p < 4; p++) {
                int r = wr + p * 4;
                Wsm[r][wc] = W[(size_t)(k0 + r) * N + bn + wc];
            }
        }
        __syncthreads();
#pragma unroll
        for (int kk = 0; kk < BK; kk++) {
            float a[4], w[4];
#pragma unroll
            for (int i = 0; i < 4; i++) a[i] = Asm[kk][tr * 4 + i];
#pragma unroll
            for (int j = 0; j < 4; j++) w[j] = Wsm[kk][tc * 4 + j];
#pragma unroll
            for (int i = 0; i < 4; i++)
#pragma unroll
                for (int j = 0; j < 4; j++)
                    acc[i][j] += a[i] * w[j];
        }
        __syncthreads();
    }
#pragma unroll
    for (int i = 0; i < 4; i++) {
        int r = bm + tr * 4 + i;
#pragma unroll
        for (int j = 0; j < 4; j++) {
            int cn = bn + tc * 4 + j;
            float v = acc[i][j];
            if (bias) v += bias[cn];
            if (has_act) v = (v >= 0.f) ? v : v * slope;
            C[(size_t)r * N + cn] = v;
        }
    }
}

// ---------------------------------------------------------------------------
// Batched fp32 [R,C] -> bf16 [C,R] transpose-convert, 12 slices in one launch
// ---------------------------------------------------------------------------
struct TPackAll {
    const float* in[12];
    bf16* out[12];
    int R[12], C[12];
};

__global__ __launch_bounds__(256) void transpose_batch(TPackAll pk)
{
    int z = blockIdx.z;
    int R = pk.R[z], C = pk.C[z];
    int c0 = blockIdx.x * 32;
    int r0 = blockIdx.y * 32;
    if (c0 >= C || r0 >= R) return;
    const float* in = pk.in[z];
    bf16* out = pk.out[z];
    __shared__ float tile[32][33];
    int tx = threadIdx.x & 31;
    int ty = threadIdx.x >> 5;
#pragma unroll
    for (int k = 0; k < 4; k++) {
        int r = ty + k * 8;
        tile[r][tx] = in[(size_t)(r0 + r) * C + c0 + tx];
    }
    __syncthreads();
#pragma unroll
    for (int k = 0; k < 4; k++) {
        int rr = ty + k * 8;
        out[(size_t)(c0 + rr) * R + r0 + tx] = f2b(tile[tx][rr]);
    }
}

__global__ void f2b_vec(const float* __restrict__ in, bf16* __restrict__ out, int n)
{
    int i = blockIdx.x * 256 + threadIdx.x;
    if (i < n) out[i] = f2b(in[i]);
}

// ---------------------------------------------------------------------------
// CSR build over dst (self loops: edge ids [EE, ET) are node e-EE)
// ---------------------------------------------------------------------------
__global__ void count_deg(const int* __restrict__ ei, int* __restrict__ deg)
{
    int e = blockIdx.x * 256 + threadIdx.x;
    if (e >= ET) return;
    int d = (e < EE) ? ei[EE + e] : (e - EE);
    d = clampi(d, 0, NN - 1);
    atomicAdd(&deg[d], 1);
}

__global__ __launch_bounds__(256) void scan_deg(const int* __restrict__ deg,
                                                int* __restrict__ rs)
{
    __shared__ int part[256];
    __shared__ int psum[257];
    int tid = threadIdx.x;
    const int per = NN / 256;
    int base = tid * per;
    int s = 0;
    for (int i = 0; i < per; i++) s += deg[base + i];
    part[tid] = s;
    __syncthreads();
    if (tid == 0) {
        int acc = 0;
        for (int i = 0; i < 256; i++) { psum[i] = acc; acc += part[i]; }
        psum[256] = acc;
    }
    __syncthreads();
    int acc = psum[tid];
    for (int i = 0; i < per; i++) { rs[base + i] = acc; acc += deg[base + i]; }
    if (tid == 0) rs[NN] = psum[256];
}

__global__ void fill_csr(const int* __restrict__ ei, const int* __restrict__ rs,
                         int* __restrict__ cur, int* __restrict__ csrc)
{
    int e = blockIdx.x * 256 + threadIdx.x;
    if (e >= ET) return;
    int s, d;
    if (e < EE) { s = ei[e]; d = ei[EE + e]; } else { s = d = e - EE; }
    s = clampi(s, 0, NN - 1);
    d = clampi(d, 0, NN - 1);
    int pos = atomicAdd(&cur[d], 1);
    int slot = clampi(rs[d] + pos, 0, ET - 1);
    csrc[slot] = s;
}

// ---------------------------------------------------------------------------
// GATv2 edge phase, fp8-gather variant (HC=1024, heads=2). Wave-per-node,
// R6 rotation depth-3 prefetch, online softmax. Rows: 16 fp8 + 1 bf16 scale
// per lane — halves the fabric-bound gather traffic (measured 150->~80 us).
// ---------------------------------------------------------------------------
__global__ __launch_bounds__(256, 4) void gat_q(
    const unsigned char* __restrict__ xlq, const bf16* __restrict__ xls,
    const bf16* __restrict__ xr, const float* __restrict__ att,
    const float* __restrict__ bias, const int* __restrict__ rs,
    const int* __restrict__ csrc, bf16* __restrict__ out_b)
{
    constexpr int HC = 1024, CPL = 16;
    const int tid = threadIdx.x;
    const int w = tid >> 6;
    const int lane = tid & 63;
    const int n = blockIdx.x * 4 + w;
    const int c0 = lane * CPL;

    int start = rs[n];
    int deg = clampi(rs[n + 1] - start, 1, 64);
    start = clampi(start, 0, ET - 1);
    int my_src = 0;
    if (lane < deg) my_src = clampi(csrc[start + lane], 0, NN - 1);

    float av[CPL], rv[CPL];
    {
        bf16x8 r0 = *(const bf16x8*)(xr + (size_t)n * HC + c0);
        bf16x8 r1 = *(const bf16x8*)(xr + (size_t)n * HC + c0 + 8);
#pragma unroll
        for (int k = 0; k < 8; k++) { rv[k] = sb2f(r0[k]); rv[8 + k] = sb2f(r1[k]); }
#pragma unroll
        for (int k = 0; k < CPL; k++) av[k] = att[c0 + k];
    }

    float m = -1e30f, den = 0.f;
    float acc[CPL];
#pragma unroll
    for (int k = 0; k < CPL; k++) acc[k] = 0.f;

    auto loadrow = [&](int i, uint4& q, float& sc) {
        int s = __shfl(my_src, i);
        q = *(const uint4*)(xlq + (size_t)s * HC + c0);
        sc = b2f(xls[(size_t)s * 64 + lane]);
    };
    auto process = [&](const uint4& q, float sc) {
        float x[CPL];
        const unsigned* qw = (const unsigned*)&q;
#pragma unroll
        for (int k = 0; k < CPL; k++)
            x[k] = dec_e4m3((qw[k >> 2] >> ((k & 3) * 8)) & 255u) * sc;
        float part = 0.f;
#pragma unroll
        for (int k = 0; k < CPL; k++) {
            float u = x[k] + rv[k];
            u = (u >= 0.f) ? u : 0.2f * u;
            part = fmaf(av[k], u, part);
        }
#pragma unroll
        for (int msk = 16; msk; msk >>= 1) part += __shfl_xor(part, msk);
        float lg = part;
        float mn = fmaxf(m, lg);
        float r = __expf(m - mn);
        float pi = __expf(lg - mn);
        m = mn;
        den = den * r + pi;
#pragma unroll
        for (int k = 0; k < CPL; k++) acc[k] = fmaf(acc[k], r, pi * x[k]);
    };

    uint4 cq, q1, q2, qn;
    float cs, s1, s2, sn;
    loadrow(0, cq, cs);
    if (deg > 1) loadrow(1, q1, s1);
    if (deg > 2) loadrow(2, q2, s2);
    for (int i = 0; i < deg; i++) {
        if (i + 3 < deg) loadrow(i + 3, qn, sn);
        process(cq, cs);
        cq = q1; cs = s1; q1 = q2; s1 = s2; q2 = qn; s2 = sn;
    }

    float inv = 1.f / den;
    bf16x8 ov0, ov1;
#pragma unroll
    for (int k = 0; k < 8; k++) {
        float v = fmaf(acc[k], inv, bias[c0 + k]);
        v = (v >= 0.f) ? v : 0.01f * v;
        ov0[k] = f2bs(v);
        float v2 = fmaf(acc[8 + k], inv, bias[c0 + 8 + k]);
        v2 = (v2 >= 0.f) ? v2 : 0.01f * v2;
        ov1[k] = f2bs(v2);
    }
    *(bf16x8*)(out_b + (size_t)n * HC + c0) = ov0;
    *(bf16x8*)(out_b + (size_t)n * HC + c0 + 8) = ov1;
}

// ---------------------------------------------------------------------------
// GATv2 edge phase, bf16-gather (L4: HC=512, residual + LN sums).
// ---------------------------------------------------------------------------
__global__ __launch_bounds__(256) void gat_b512(
    const bf16* __restrict__ xl, const bf16* __restrict__ xr,
    const float* __restrict__ att, const float* __restrict__ bias,
    const int* __restrict__ rs, const int* __restrict__ csrc,
    const bf16* __restrict__ res, bf16* __restrict__ out_b,
    float* __restrict__ lnsums)
{
    constexpr int HC = 512, CPL = 8;
    const int tid = threadIdx.x;
    const int w = tid >> 6;
    const int lane = tid & 63;
    const int n = blockIdx.x * 4 + w;
    const int c0 = lane * CPL;

    int start = rs[n];
    int deg = clampi(rs[n + 1] - start, 1, 64);
    start = clampi(start, 0, ET - 1);
    int my_src = 0;
    if (lane < deg) my_src = clampi(csrc[start + lane], 0, NN - 1);

    float av[CPL], rv[CPL];
    {
        bf16x8 rp = *(const bf16x8*)(xr + (size_t)n * HC + c0);
#pragma unroll
        for (int k = 0; k < CPL; k++) {
            rv[k] = sb2f(rp[k]);
            av[k] = att[c0 + k];
        }
    }

    float m = -1e30f, den = 0.f;
    float acc[CPL];
#pragma unroll
    for (int k = 0; k < CPL; k++) acc[k] = 0.f;

    auto loadrow = [&](int i, bf16x8& dst) {
        int s = __shfl(my_src, i);
        dst = *(const bf16x8*)(xl + (size_t)s * HC + c0);
    };

    bf16x8 cur, nx1, nx2, nxt;
    loadrow(0, cur);
    if (deg > 1) loadrow(1, nx1);
    if (deg > 2) loadrow(2, nx2);

    for (int i = 0; i < deg; i++) {
        if (i + 3 < deg) loadrow(i + 3, nxt);
        float part = 0.f;
#pragma unroll
        for (int k = 0; k < CPL; k++) {
            float x = sb2f(cur[k]);
            float u = x + rv[k];
            u = (u >= 0.f) ? u : 0.2f * u;
            part = fmaf(av[k], u, part);
        }
#pragma unroll
        for (int msk = 32; msk; msk >>= 1) part += __shfl_xor(part, msk);
        float lg = part;
        float mn = fmaxf(m, lg);
        float r = __expf(m - mn);
        float pi = __expf(lg - mn);
        m = mn;
        den = den * r + pi;
#pragma unroll
        for (int k = 0; k < CPL; k++) {
            float x = sb2f(cur[k]);
            acc[k] = fmaf(acc[k], r, pi * x);
        }
        cur = nx1; nx1 = nx2; nx2 = nxt;
    }

    float inv = 1.f / den;
    float ls = 0.f, ls2 = 0.f;
    float vals[CPL];
#pragma unroll
    for (int k = 0; k < CPL; k++) {
        float v = fmaf(acc[k], inv, bias[c0 + k]);
        v = (v >= 0.f) ? v : 0.01f * v;
        vals[k] = v;
    }
    {
        bf16x8 rr = *(const bf16x8*)(res + (size_t)n * HC + c0);
#pragma unroll
        for (int k = 0; k < CPL; k++) {
            vals[k] += sb2f(rr[k]);
            ls += vals[k];
            ls2 += vals[k] * vals[k];
        }
    }
    bf16x8 ov;
#pragma unroll
    for (int k = 0; k < 8; k++) ov[k] = f2bs(vals[k]);
    *(bf16x8*)(out_b + (size_t)n * HC + c0) = ov;

#pragma unroll
    for (int msk = 32; msk; msk >>= 1) {
        ls += __shfl_xor(ls, msk);
        ls2 += __shfl_xor(ls2, msk);
    }
    if (lane == 0) {
        int g = n >> 8;
        atomicAdd(&lnsums[g], ls);
        atomicAdd(&lnsums[BBG + g], ls2);
    }
}

// ---------------------------------------------------------------------------
// LN apply + channel-wise online-softmax aggregation (bf16 h), partials.
// ---------------------------------------------------------------------------
__global__ __launch_bounds__(256) void aggr_partial(
    const bf16* __restrict__ h, const float* __restrict__ lnsums,
    const float* __restrict__ lnw, const float* __restrict__ lnb,
    const float* __restrict__ t_, float* __restrict__ pm,
    float* __restrict__ pd, float* __restrict__ pa)
{
    int g = blockIdx.x, ch = blockIdx.y, nk = blockIdx.z;
    int tid = threadIdx.x;
    int c = ch * 256 + tid;
    const float tot = (float)(NG * DD);
    float S = lnsums[g], S2 = lnsums[BBG + g];
    float mu = S / tot;
    float iv = rsqrtf(fmaxf(S2 / tot - mu * mu, 0.f) + 1e-5f);
    float w = lnw[c], b = lnb[c], t = t_[0];
    size_t base = (size_t)g * NG * DD + (size_t)nk * 32 * DD + c;
    float m = -1e30f, den = 0.f, acc = 0.f;
    for (int i = 0; i < 32; i++) {
        float hn = (b2f(h[base + (size_t)i * DD]) - mu) * iv * w + b;
        float lg = hn * t;
        if (lg > m) {
            float r = __expf(m - lg);
            den *= r; acc *= r; m = lg;
        }
        float p = __expf(lg - m);
        den += p; acc += p * hn;
    }
    size_t idx = (((size_t)g * 2 + ch) * 8 + nk) * 256 + tid;
    pm[idx] = m; pd[idx] = den; pa[idx] = acc;
}

__global__ __launch_bounds__(256) void aggr_combine(
    const float* __restrict__ pm, const float* __restrict__ pd,
    const float* __restrict__ pa, float* __restrict__ gout)
{
    int g = blockIdx.x, ch = blockIdx.y;
    int tid = threadIdx.x;
    size_t base = (((size_t)g * 2 + ch) * 8) * 256 + tid;
    float m = -1e30f;
#pragma unroll
    for (int k = 0; k < 8; k++) m = fmaxf(m, pm[base + k * 256]);
    float den = 0.f, acc = 0.f;
#pragma unroll
    for (int k = 0; k < 8; k++) {
        float r = __expf(pm[base + k * 256] - m);
        den += pd[base + k * 256] * r;
        acc += pa[base + k * 256] * r;
    }
    gout[(size_t)g * DD + ch * 256 + tid] = acc / den;
}

// ---------------------------------------------------------------------------
extern "C" void kernel_launch(void* const* d_in, const int* in_sizes, int n_in,
                              void* d_out, int out_size, void* d_ws, size_t ws_size,
                              hipStream_t stream)
{
    const float* x      = (const float*)d_in[0];
    const int*   ei     = (const int*)d_in[1];
    const float* xt_w1  = (const float*)d_in[3];
    const float* xt_b1  = (const float*)d_in[4];
    const float* xt_w2  = (const float*)d_in[5];
    const float* xt_b2  = (const float*)d_in[6];
    const float* ln_w   = (const float*)d_in[27];
    const float* ln_b   = (const float*)d_in[28];
    const float* aggr_t = (const float*)d_in[29];
    const float* m_w1   = (const float*)d_in[30];
    const float* m_b1   = (const float*)d_in[31];
    const float* m_w2   = (const float*)d_in[32];
    const float* m_b2   = (const float*)d_in[33];
    const float* m_w3   = (const float*)d_in[34];
    const float* m_b3   = (const float*)d_in[35];
    float* out = (float*)d_out;

    // ---- workspace layout (256B aligned); ints first ----
    char* p = (char*)d_ws;
    auto take = [&](size_t bytes) {
        char* r = p;
        p += (bytes + 255) & ~(size_t)255;
        return r;
    };
    int* i_deg     = (int*)take((size_t)(NN + 1) * 4);
    int* i_rs      = (int*)take((size_t)(NN + 1) * 4);
    int* i_cur     = (int*)take((size_t)NN * 4);
    int* i_src     = (int*)take((size_t)ET * 4);
    float* f_sums  = (float*)take((size_t)2 * BBG * 4);
    float* f_pm    = (float*)take((size_t)BBG * 2 * 8 * 256 * 4);
    float* f_pd    = (float*)take((size_t)BBG * 2 * 8 * 256 * 4);
    float* f_pa    = (float*)take((size_t)BBG * 2 * 8 * 256 * 4);
    float* b_g     = (float*)take((size_t)BBG * DD * 4);
    float* b_m1    = (float*)take((size_t)BBG * 384 * 4);
    float* b_m2    = (float*)take((size_t)BBG * 256 * 4);
    bf16* b_resb   = (bf16*)take((size_t)NN * DD * 2);       // bf16 cx/residual
    bf16* b_h      = (bf16*)take((size_t)NN * DD * 2);       // bf16 final h (L4)
    bf16* b_hb     = (bf16*)take((size_t)NN * 1024 * 2);     // bf16 h (alias t1b)
    bf16* b_xlb    = (bf16*)take((size_t)NN * 1024 * 2);     // bf16 xl
    bf16* b_xrb    = (bf16*)take((size_t)NN * 1024 * 2);     // bf16 xr
    unsigned char* b_xlq = (unsigned char*)take((size_t)NN * 1024); // fp8 xl
    bf16* b_xls    = (bf16*)take((size_t)NN * 64 * 2);       // per-16ch scales
    bf16* b_xb     = (bf16*)take((size_t)2 * NN * 32 * 2);
    bf16* b_wcat   = (bf16*)take((size_t)8 * 1024 * 1024 * 2); // all [wlT;wrT]
    bf16* b_w1b    = (bf16*)take((size_t)32 * 256 * 2);
    bf16* b_w2b    = (bf16*)take((size_t)256 * 256 * 2);
    bf16* b_t1b = b_hb;

    // wcat element offsets per layer
    size_t woff[5];
    {
        size_t o = 0;
        for (int L = 0; L < 5; L++) {
            int Fin = (L == 0) ? 512 : 1024;
            int HC  = (L == 4) ? 512 : 1024;
            woff[L] = o;
            o += (size_t)2 * HC * Fin;
        }
    }

    dim3 blk(256);

    // ---- CSR build + LN-sum zero ----
    hipMemsetAsync(i_deg, 0, (size_t)(NN + 1) * 4, stream);
    hipMemsetAsync(i_cur, 0, (size_t)NN * 4, stream);
    hipMemsetAsync(f_sums, 0, (size_t)2 * BBG * 4, stream);
    count_deg<<<ET / 256, blk, 0, stream>>>(ei, i_deg);
    scan_deg<<<1, blk, 0, stream>>>(i_deg, i_rs);
    fill_csr<<<ET / 256, blk, 0, stream>>>(ei, i_rs, i_cur, i_src);

    // ---- x convert + ALL weight transposes in one launch ----
    f2b_vec<<<(2 * NN * 32 + 255) / 256, blk, 0, stream>>>(x, b_xb, 2 * NN * 32);
    {
        TPackAll pk;
        pk.in[0] = xt_w1; pk.out[0] = b_w1b; pk.R[0] = 32;  pk.C[0] = 256;
        pk.in[1] = xt_w2; pk.out[1] = b_w2b; pk.R[1] = 256; pk.C[1] = 256;
        for (int L = 0; L < 5; L++) {
            int Fin = (L == 0) ? 512 : 1024;
            int HC  = (L == 4) ? 512 : 1024;
            pk.in[2 + 2 * L] = (const float*)d_in[7 + 4 * L];      // wl
            pk.out[2 + 2 * L] = b_wcat + woff[L];
            pk.R[2 + 2 * L] = Fin; pk.C[2 + 2 * L] = HC;
            pk.in[3 + 2 * L] = (const float*)d_in[8 + 4 * L];      // wr
            pk.out[3 + 2 * L] = b_wcat + woff[L] + (size_t)HC * Fin;
            pk.R[3 + 2 * L] = Fin; pk.C[3 + 2 * L] = HC;
        }
        transpose_batch<<<dim3(32, 32, 12), blk, 0, stream>>>(pk);
    }

    // ---- x_trans ----
    gemm_mfma_bt<<<dim3(256 / 128, 32768 / 128), blk, 0, stream>>>(
        b_xb, b_w1b, xt_b1, b_t1b, 32768, 256, 32, 0.01f, 1);
    gemm_mfma_bt<<<dim3(256 / 128, 32768 / 128), blk, 0, stream>>>(
        b_t1b, b_w2b, xt_b2, b_resb, 32768, 256, 256, 0.f, 0);

    // ---- 5 GATv2 layers (L0-3: fp8 gathers; L4: bf16 + residual + LN) ----
    for (int L = 0; L < 5; L++) {
        const float* att = (const float*)d_in[9 + 4 * L];
        const float* gb  = (const float*)d_in[10 + 4 * L];
        int Fin = (L == 0) ? 512 : 1024;
        int HC  = (L == 4) ? 512 : 1024;
        const bf16* hin = (L == 0) ? b_resb : b_hb;

        gemm_mfma_dual<<<dim3(2 * HC / 128, NN / 128), blk, 0, stream>>>(
            hin, b_wcat + woff[L], b_xlb, b_xrb, NN, Fin, HC);
        if (L < 4) {
            quant_rows<<<NN / 4, blk, 0, stream>>>(b_xlb, b_xlq, b_xls);
            gat_q<<<NN / 4, blk, 0, stream>>>(
                b_xlq, b_xls, b_xrb, att, gb, i_rs, i_src, b_hb);
        } else {
            gat_b512<<<NN / 4, blk, 0, stream>>>(
                b_xlb, b_xrb, att, gb, i_rs, i_src, b_resb, b_h, f_sums);
        }
    }

    // ---- graph LN + softmax aggregation ----
    aggr_partial<<<dim3(BBG, 2, 8), blk, 0, stream>>>(
        b_h, f_sums, ln_w, ln_b, aggr_t, f_pm, f_pd, f_pa);
    aggr_combine<<<dim3(BBG, 2), blk, 0, stream>>>(f_pm, f_pd, f_pa, b_g);

    // ---- head MLP 512 -> 384 -> 256 -> 128 (fp32) ----
    gemm_f32<<<dim3(384 / 64, 1), blk, 0, stream>>>(
        b_g, m_w1, m_b1, b_m1, 64, 384, 512, 0.01f, 1);
    gemm_f32<<<dim3(256 / 64, 1), blk, 0, stream>>>(
        b_m1, m_w2, m_b2, b_m2, 64, 256, 384, 0.01f, 1);
    gemm_f32<<<dim3(128 / 64, 1), blk, 0, stream>>>(
        b_m2, m_w3, m_b3, out, 64, 128, 256, 0.f, 0);
}

// Round 10
// 1062.765 us; speedup vs baseline: 1.0940x; 1.0217x over previous
//
#include <hip/hip_runtime.h>
#include <hip/hip_bf16.h>

typedef __hip_bfloat16 bf16;

#define NN 16384          // gate nodes
#define BBG 64            // graphs
#define EE 49152          // directed edges (no self loops)
#define ET (EE + NN)      // edges + self loops = 65536
#define DD 512            // node feature dim (2F)
#define NG (NN / BBG)     // 256 nodes per graph
#define RS1024 1152       // packed fp8 row stride, HC=1024: 128B scales + 1024B data
#define RS512  640        // packed fp8 row stride, HC=512:  128B scales + 512B data

__device__ __forceinline__ float b2f(bf16 v) { return __bfloat162float(v); }
__device__ __forceinline__ bf16 f2b(float v) { return __float2bfloat16(v); }
__device__ __forceinline__ float sb2f(short s) {
    unsigned u = ((unsigned)(unsigned short)s) << 16;
    return __builtin_bit_cast(float, u);
}
__device__ __forceinline__ short f2bs(float v) {
    bf16 b = f2b(v);
    return __builtin_bit_cast(short, b);
}
__device__ __forceinline__ int clampi(int v, int lo, int hi)
{
    return v < lo ? lo : (v > hi ? hi : v);
}

// ---- OCP e4m3fn encode/decode (manual, self-contained) ----
__device__ __forceinline__ unsigned char enc_e4m3(float y)
{
    unsigned b = __builtin_bit_cast(unsigned, y);
    unsigned s = (b >> 31) << 7;
    float a = fabsf(y);
    unsigned ab = b & 0x7fffffffu;
    unsigned rb = ab + (1u << 19);            // round half-up at mantissa bit 20
    int e = (int)(rb >> 23) - 120;
    unsigned m = (rb >> 20) & 7u;
    unsigned qn = (unsigned)(e << 3) | m;
    if (qn > 126u) qn = 126u;                 // clamp to 448, never NaN encoding
    unsigned qd = (unsigned)__float2int_rn(a * 512.f);  // denormal
    unsigned q = (a < 0.015625f) ? qd : qn;
    return (unsigned char)(q | s);
}
__device__ __forceinline__ float dec_e4m3(unsigned q)
{
    unsigned e = (q >> 3) & 15u, m = q & 7u;
    float nrm = __builtin_bit_cast(float, ((e + 120u) << 23) | (m << 20));
    float dnm = (float)m * 0.001953125f;      // m * 2^-9
    float v = e ? nrm : dnm;
    return (q & 128u) ? -v : v;
}

typedef __attribute__((ext_vector_type(8))) short bf16x8;  // 8 bf16 = 4 VGPRs
typedef __attribute__((ext_vector_type(4))) float f32x4;

#define AS1 __attribute__((address_space(1)))
#define AS3 __attribute__((address_space(3)))

// ---------------------------------------------------------------------------
// MFMA bf16 GEMM: C = act(A @ Bt^T + bias). Used for x_trans.
// ---------------------------------------------------------------------------
__global__ __launch_bounds__(256) void gemm_mfma_bt(
    const bf16* __restrict__ A, const bf16* __restrict__ Bt,
    const float* __restrict__ bias, bf16* __restrict__ Cb,
    int M, int N, int K, float slope, int has_act)
{
    __shared__ bf16 As[128 * 32];
    __shared__ bf16 Bs[128 * 32];
    const int tid = threadIdx.x;
    const int w = tid >> 6;
    const int l = tid & 63;
    const int bm = blockIdx.y * 128;
    const int bn = blockIdx.x * 128;
    const int wrow = (w >> 1) * 64;
    const int wcol = (w & 1) * 64;
    const int quad = l >> 4;
    const int c16 = l & 15;

    const int lrow = l >> 2;
    const int lchunk = l & 3;
    const bf16* Ag = A + (size_t)(bm + w * 16 + lrow) * K + lchunk * 8;
    const bf16* Bg = Bt + (size_t)(bn + w * 16 + lrow) * K + lchunk * 8;
    char* AsB = (char*)As;
    char* BsB = (char*)Bs;

    f32x4 acc[4][4] = {};

    for (int k0 = 0; k0 < K; k0 += 32) {
        __builtin_amdgcn_global_load_lds((const AS1 void*)(Ag + k0),
            (AS3 void*)(AsB + w * 1024), 16, 0, 0);
        __builtin_amdgcn_global_load_lds((const AS1 void*)(Ag + (size_t)64 * K + k0),
            (AS3 void*)(AsB + 4096 + w * 1024), 16, 0, 0);
        __builtin_amdgcn_global_load_lds((const AS1 void*)(Bg + k0),
            (AS3 void*)(BsB + w * 1024), 16, 0, 0);
        __builtin_amdgcn_global_load_lds((const AS1 void*)(Bg + (size_t)64 * K + k0),
            (AS3 void*)(BsB + 4096 + w * 1024), 16, 0, 0);
        __syncthreads();

        bf16x8 a[4], b[4];
#pragma unroll
        for (int i = 0; i < 4; i++) {
            int ra = wrow + i * 16 + c16;
            a[i] = *(const bf16x8*)(AsB + ra * 64 + quad * 16);
            int rb = wcol + i * 16 + c16;
            b[i] = *(const bf16x8*)(BsB + rb * 64 + quad * 16);
        }
#pragma unroll
        for (int i = 0; i < 4; i++)
#pragma unroll
            for (int j = 0; j < 4; j++)
                acc[i][j] = __builtin_amdgcn_mfma_f32_16x16x32_bf16(
                    a[i], b[j], acc[i][j], 0, 0, 0);
        __syncthreads();
    }

#pragma unroll
    for (int i = 0; i < 4; i++) {
#pragma unroll
        for (int j = 0; j < 4; j++) {
            int col = bn + wcol + j * 16 + c16;
            float bv = bias ? bias[col] : 0.f;
#pragma unroll
            for (int r = 0; r < 4; r++) {
                int row = bm + wrow + i * 16 + quad * 4 + r;
                float v = acc[i][j][r] + bv;
                if (has_act) v = (v >= 0.f) ? v : v * slope;
                Cb[(size_t)row * N + col] = f2b(v);
            }
        }
    }
}

// ---------------------------------------------------------------------------
// Merged dual GEMM: Bt = [wlT; wrT]. cols [0,HC) -> X0, [HC,2HC) -> X1 (bf16)
// ---------------------------------------------------------------------------
__global__ __launch_bounds__(256) void gemm_mfma_dual(
    const bf16* __restrict__ A, const bf16* __restrict__ Bt,
    bf16* __restrict__ X0, bf16* __restrict__ X1,
    int M, int K, int HC)
{
    __shared__ bf16 As[128 * 32];
    __shared__ bf16 Bs[128 * 32];
    const int tid = threadIdx.x;
    const int w = tid >> 6;
    const int l = tid & 63;
    const int bm = blockIdx.y * 128;
    const int bn = blockIdx.x * 128;
    const int wrow = (w >> 1) * 64;
    const int wcol = (w & 1) * 64;
    const int quad = l >> 4;
    const int c16 = l & 15;

    const int lrow = l >> 2;
    const int lchunk = l & 3;
    const bf16* Ag = A + (size_t)(bm + w * 16 + lrow) * K + lchunk * 8;
    const bf16* Bg = Bt + (size_t)(bn + w * 16 + lrow) * K + lchunk * 8;
    char* AsB = (char*)As;
    char* BsB = (char*)Bs;

    f32x4 acc[4][4] = {};

    for (int k0 = 0; k0 < K; k0 += 32) {
        __builtin_amdgcn_global_load_lds((const AS1 void*)(Ag + k0),
            (AS3 void*)(AsB + w * 1024), 16, 0, 0);
        __builtin_amdgcn_global_load_lds((const AS1 void*)(Ag + (size_t)64 * K + k0),
            (AS3 void*)(AsB + 4096 + w * 1024), 16, 0, 0);
        __builtin_amdgcn_global_load_lds((const AS1 void*)(Bg + k0),
            (AS3 void*)(BsB + w * 1024), 16, 0, 0);
        __builtin_amdgcn_global_load_lds((const AS1 void*)(Bg + (size_t)64 * K + k0),
            (AS3 void*)(BsB + 4096 + w * 1024), 16, 0, 0);
        __syncthreads();

        bf16x8 a[4], b[4];
#pragma unroll
        for (int i = 0; i < 4; i++) {
            int ra = wrow + i * 16 + c16;
            a[i] = *(const bf16x8*)(AsB + ra * 64 + quad * 16);
            int rb = wcol + i * 16 + c16;
            b[i] = *(const bf16x8*)(BsB + rb * 64 + quad * 16);
        }
#pragma unroll
        for (int i = 0; i < 4; i++)
#pragma unroll
            for (int j = 0; j < 4; j++)
                acc[i][j] = __builtin_amdgcn_mfma_f32_16x16x32_bf16(
                    a[i], b[j], acc[i][j], 0, 0, 0);
        __syncthreads();
    }

#pragma unroll
    for (int i = 0; i < 4; i++) {
#pragma unroll
        for (int j = 0; j < 4; j++) {
            int col = bn + wcol + j * 16 + c16;
            bf16* dst = (col < HC) ? (X0 + col) : (X1 + col - HC);
#pragma unroll
            for (int r = 0; r < 4; r++) {
                int row = bm + wrow + i * 16 + quad * 4 + r;
                dst[(size_t)row * HC] = f2b(acc[i][j][r]);
            }
        }
    }
}

// ---------------------------------------------------------------------------
// Row quantizers -> PACKED rows: [scales bf16 x64 | fp8 data], co-located so
// the per-edge scale fetch shares the DRAM row with the data fetch.
// HC=1024: stride 1152, lane owns 16 ch (per-16 scale).
// HC=512:  stride 640,  lane owns 8 ch (per-8 scale).
// ---------------------------------------------------------------------------
__global__ __launch_bounds__(256, 4) void quant1024(
    const bf16* __restrict__ xl, unsigned char* __restrict__ xp)
{
    const int n = blockIdx.x * 4 + (threadIdx.x >> 6);
    const int lane = threadIdx.x & 63;
    const bf16* rp = xl + (size_t)n * 1024 + lane * 16;
    bf16x8 v0 = *(const bf16x8*)(rp);
    bf16x8 v1 = *(const bf16x8*)(rp + 8);
    float x[16];
#pragma unroll
    for (int k = 0; k < 8; k++) { x[k] = sb2f(v0[k]); x[8 + k] = sb2f(v1[k]); }
    float mx = 0.f;
#pragma unroll
    for (int k = 0; k < 16; k++) mx = fmaxf(mx, fabsf(x[k]));
    float sc = b2f(f2b(fmaxf(mx, 1e-20f) * (1.f / 448.f)));
    float isc = 1.f / sc;
    uint4 q;
    unsigned* qw = (unsigned*)&q;
#pragma unroll
    for (int w = 0; w < 4; w++) {
        unsigned pk = 0;
#pragma unroll
        for (int b = 0; b < 4; b++)
            pk |= ((unsigned)enc_e4m3(x[w * 4 + b] * isc)) << (b * 8);
        qw[w] = pk;
    }
    unsigned char* row = xp + (size_t)n * RS1024;
    *(uint4*)(row + 128 + lane * 16) = q;
    ((bf16*)row)[lane] = f2b(sc);
}

__global__ __launch_bounds__(256, 4) void quant512(
    const bf16* __restrict__ xl, unsigned char* __restrict__ xp)
{
    const int n = blockIdx.x * 4 + (threadIdx.x >> 6);
    const int lane = threadIdx.x & 63;
    bf16x8 v0 = *(const bf16x8*)(xl + (size_t)n * 512 + lane * 8);
    float x[8];
#pragma unroll
    for (int k = 0; k < 8; k++) x[k] = sb2f(v0[k]);
    float mx = 0.f;
#pragma unroll
    for (int k = 0; k < 8; k++) mx = fmaxf(mx, fabsf(x[k]));
    float sc = b2f(f2b(fmaxf(mx, 1e-20f) * (1.f / 448.f)));
    float isc = 1.f / sc;
    uint2 q;
    unsigned* qw = (unsigned*)&q;
#pragma unroll
    for (int w = 0; w < 2; w++) {
        unsigned pk = 0;
#pragma unroll
        for (int b = 0; b < 4; b++)
            pk |= ((unsigned)enc_e4m3(x[w * 4 + b] * isc)) << (b * 8);
        qw[w] = pk;
    }
    unsigned char* row = xp + (size_t)n * RS512;
    *(uint2*)(row + 128 + lane * 8) = q;
    ((bf16*)row)[lane] = f2b(sc);
}

// ---------------------------------------------------------------------------
// fp32 GEMM (head MLP only)
// ---------------------------------------------------------------------------
__global__ __launch_bounds__(256) void gemm_f32(
    const float* __restrict__ A, const float* __restrict__ W,
    const float* __restrict__ bias, float* __restrict__ C,
    int M, int N, int K, float slope, int has_act)
{
    const int BK = 16;
    __shared__ float Asm[BK][64 + 1];
    __shared__ float Wsm[BK][64 + 1];
    int tid = threadIdx.x;
    int bm = blockIdx.y * 64;
    int bn = blockIdx.x * 64;
    int tr = tid >> 4;
    int tc = tid & 15;
    float acc[4][4] = {};

    for (int k0 = 0; k0 < K; k0 += BK) {
        {
            int col = tid & 15;
            int row = tid >> 4;
#pragma unroll
            for (int p = 0; p < 4; p++) {
                int r = row + p * 16;
                Asm[col][r] = A[(size_t)(bm + r) * K + k0 + col];
            }
        }
        {
            int wc = tid & 63;
            int wr = tid >> 6;
#pragma unroll
            for (int p = 0; p < 4; p++) {
                int r = wr + p * 4;
                Wsm[r][wc] = W[(size_t)(k0 + r) * N + bn + wc];
            }
        }
        __syncthreads();
#pragma unroll
        for (int kk = 0; kk < BK; kk++) {
            float a[4], w[4];
#pragma unroll
            for (int i = 0; i < 4; i++) a[i] = Asm[kk][tr * 4 + i];
#pragma unroll
            for (int j = 0; j < 4; j++) w[j] = Wsm[kk][tc * 4 + j];
#pragma unroll
            for (int i = 0; i < 4; i++)
#pragma unroll
                for (int j = 0; j < 4; j++)
                    acc[i][j] += a[i] * w[j];
        }
        __syncthreads();
    }
#pragma unroll
    for (int i = 0; i < 4; i++) {
        int r = bm + tr * 4 + i;
#pragma unroll
        for (int j = 0; j < 4; j++) {
            int cn = bn + tc * 4 + j;
            float v = acc[i][j];
            if (bias) v += bias[cn];
            if (has_act) v = (v >= 0.f) ? v : v * slope;
            C[(size_t)r * N + cn] = v;
        }
    }
}

// ---------------------------------------------------------------------------
// Batched fp32 [R,C] -> bf16 [C,R] transpose-convert, 12 slices in one launch
// ---------------------------------------------------------------------------
struct TPackAll {
    const float* in[12];
    bf16* out[12];
    int R[12], C[12];
};

__global__ __launch_bounds__(256) void transpose_batch(TPackAll pk)
{
    int z = blockIdx.z;
    int R = pk.R[z], C = pk.C[z];
    int c0 = blockIdx.x * 32;
    int r0 = blockIdx.y * 32;
    if (c0 >= C || r0 >= R) return;
    const float* in = pk.in[z];
    bf16* out = pk.out[z];
    __shared__ float tile[32][33];
    int tx = threadIdx.x & 31;
    int ty = threadIdx.x >> 5;
#pragma unroll
    for (int k = 0; k < 4; k++) {
        int r = ty + k * 8;
        tile[r][tx] = in[(size_t)(r0 + r) * C + c0 + tx];
    }
    __syncthreads();
#pragma unroll
    for (int k = 0; k < 4; k++) {
        int rr = ty + k * 8;
        out[(size_t)(c0 + rr) * R + r0 + tx] = f2b(tile[tx][rr]);
    }
}

__global__ void f2b_vec(const float* __restrict__ in, bf16* __restrict__ out, int n)
{
    int i = blockIdx.x * 256 + threadIdx.x;
    if (i < n) out[i] = f2b(in[i]);
}

// ---------------------------------------------------------------------------
// Bucket CSR: csrc[d][64] slots, cur[d] = in-degree (incl self loop).
// No count/scan pass; deg read directly from cur.
// ---------------------------------------------------------------------------
__global__ void fill_csr(const int* __restrict__ ei, int* __restrict__ cur,
                         int* __restrict__ csrc)
{
    int e = blockIdx.x * 256 + threadIdx.x;
    if (e >= ET) return;
    int s, d;
    if (e < EE) { s = ei[e]; d = ei[EE + e]; } else { s = d = e - EE; }
    s = clampi(s, 0, NN - 1);
    d = clampi(d, 0, NN - 1);
    int pos = atomicAdd(&cur[d], 1);
    if (pos < 64) csrc[d * 64 + pos] = s;
}

// ---------------------------------------------------------------------------
// GATv2 edge phase, packed-fp8 gathers, HC=1024 (2 heads). Wave-per-node,
// depth-3 rotation prefetch, online softmax. One row = one 1152B span:
// scale fetch + data fetch share the DRAM row.
// ---------------------------------------------------------------------------
__global__ __launch_bounds__(256, 4) void gat_q(
    const unsigned char* __restrict__ xp, const bf16* __restrict__ xr,
    const float* __restrict__ att, const float* __restrict__ bias,
    const int* __restrict__ cur, const int* __restrict__ csrc,
    bf16* __restrict__ out_b)
{
    constexpr int HC = 1024, CPL = 16;
    const int tid = threadIdx.x;
    const int w = tid >> 6;
    const int lane = tid & 63;
    const int n = blockIdx.x * 4 + w;
    const int c0 = lane * CPL;

    int deg = clampi(cur[n], 1, 64);
    int my_src = clampi(csrc[n * 64 + lane], 0, NN - 1);

    float av[CPL], rv[CPL];
    {
        bf16x8 r0 = *(const bf16x8*)(xr + (size_t)n * HC + c0);
        bf16x8 r1 = *(const bf16x8*)(xr + (size_t)n * HC + c0 + 8);
#pragma unroll
        for (int k = 0; k < 8; k++) { rv[k] = sb2f(r0[k]); rv[8 + k] = sb2f(r1[k]); }
#pragma unroll
        for (int k = 0; k < CPL; k++) av[k] = att[c0 + k];
    }

    float m = -1e30f, den = 0.f;
    float acc[CPL];
#pragma unroll
    for (int k = 0; k < CPL; k++) acc[k] = 0.f;

    auto loadrow = [&](int i, uint4& q, float& sc) {
        int s = __shfl(my_src, i);
        const unsigned char* row = xp + (size_t)s * RS1024;
        sc = b2f(*(const bf16*)(row + lane * 2));
        q = *(const uint4*)(row + 128 + lane * 16);
    };
    auto process = [&](const uint4& q, float sc) {
        float x[CPL];
        const unsigned* qw = (const unsigned*)&q;
#pragma unroll
        for (int k = 0; k < CPL; k++)
            x[k] = dec_e4m3((qw[k >> 2] >> ((k & 3) * 8)) & 255u) * sc;
        float part = 0.f;
#pragma unroll
        for (int k = 0; k < CPL; k++) {
            float u = x[k] + rv[k];
            u = (u >= 0.f) ? u : 0.2f * u;
            part = fmaf(av[k], u, part);
        }
#pragma unroll
        for (int msk = 16; msk; msk >>= 1) part += __shfl_xor(part, msk);
        float lg = part;
        float mn = fmaxf(m, lg);
        float r = __expf(m - mn);
        float pi = __expf(lg - mn);
        m = mn;
        den = den * r + pi;
#pragma unroll
        for (int k = 0; k < CPL; k++) acc[k] = fmaf(acc[k], r, pi * x[k]);
    };

    uint4 cq, q1, q2, qn;
    float cs, s1, s2, sn;
    loadrow(0, cq, cs);
    if (deg > 1) loadrow(1, q1, s1);
    if (deg > 2) loadrow(2, q2, s2);
    for (int i = 0; i < deg; i++) {
        if (i + 3 < deg) loadrow(i + 3, qn, sn);
        process(cq, cs);
        cq = q1; cs = s1; q1 = q2; s1 = s2; q2 = qn; s2 = sn;
    }

    float inv = 1.f / den;
    bf16x8 ov0, ov1;
#pragma unroll
    for (int k = 0; k < 8; k++) {
        float v = fmaf(acc[k], inv, bias[c0 + k]);
        v = (v >= 0.f) ? v : 0.01f * v;
        ov0[k] = f2bs(v);
        float v2 = fmaf(acc[8 + k], inv, bias[c0 + 8 + k]);
        v2 = (v2 >= 0.f) ? v2 : 0.01f * v2;
        ov1[k] = f2bs(v2);
    }
    *(bf16x8*)(out_b + (size_t)n * HC + c0) = ov0;
    *(bf16x8*)(out_b + (size_t)n * HC + c0 + 8) = ov1;
}

// ---------------------------------------------------------------------------
// GATv2 edge phase, packed-fp8 gathers, HC=512 (1 head) + residual + LN sums.
// ---------------------------------------------------------------------------
__global__ __launch_bounds__(256, 4) void gat_q512(
    const unsigned char* __restrict__ xp, const bf16* __restrict__ xr,
    const float* __restrict__ att, const float* __restrict__ bias,
    const int* __restrict__ cur, const int* __restrict__ csrc,
    const bf16* __restrict__ res, bf16* __restrict__ out_b,
    float* __restrict__ lnsums)
{
    constexpr int HC = 512, CPL = 8;
    const int tid = threadIdx.x;
    const int w = tid >> 6;
    const int lane = tid & 63;
    const int n = blockIdx.x * 4 + w;
    const int c0 = lane * CPL;

    int deg = clampi(cur[n], 1, 64);
    int my_src = clampi(csrc[n * 64 + lane], 0, NN - 1);

    float av[CPL], rv[CPL];
    {
        bf16x8 rp = *(const bf16x8*)(xr + (size_t)n * HC + c0);
#pragma unroll
        for (int k = 0; k < CPL; k++) {
            rv[k] = sb2f(rp[k]);
            av[k] = att[c0 + k];
        }
    }

    float m = -1e30f, den = 0.f;
    float acc[CPL];
#pragma unroll
    for (int k = 0; k < CPL; k++) acc[k] = 0.f;

    auto loadrow = [&](int i, uint2& q, float& sc) {
        int s = __shfl(my_src, i);
        const unsigned char* row = xp + (size_t)s * RS512;
        sc = b2f(*(const bf16*)(row + lane * 2));
        q = *(const uint2*)(row + 128 + lane * 8);
    };
    auto process = [&](const uint2& q, float sc) {
        float x[CPL];
        const unsigned* qw = (const unsigned*)&q;
#pragma unroll
        for (int k = 0; k < CPL; k++)
            x[k] = dec_e4m3((qw[k >> 2] >> ((k & 3) * 8)) & 255u) * sc;
        float part = 0.f;
#pragma unroll
        for (int k = 0; k < CPL; k++) {
            float u = x[k] + rv[k];
            u = (u >= 0.f) ? u : 0.2f * u;
            part = fmaf(av[k], u, part);
        }
#pragma unroll
        for (int msk = 32; msk; msk >>= 1) part += __shfl_xor(part, msk);
        float lg = part;
        float mn = fmaxf(m, lg);
        float r = __expf(m - mn);
        float pi = __expf(lg - mn);
        m = mn;
        den = den * r + pi;
#pragma unroll
        for (int k = 0; k < CPL; k++) acc[k] = fmaf(acc[k], r, pi * x[k]);
    };

    uint2 cq, q1, q2, qn;
    float cs, s1, s2, sn;
    loadrow(0, cq, cs);
    if (deg > 1) loadrow(1, q1, s1);
    if (deg > 2) loadrow(2, q2, s2);
    for (int i = 0; i < deg; i++) {
        if (i + 3 < deg) loadrow(i + 3, qn, sn);
        process(cq, cs);
        cq = q1; cs = s1; q1 = q2; s1 = s2; q2 = qn; s2 = sn;
    }

    float inv = 1.f / den;
    float ls = 0.f, ls2 = 0.f;
    float vals[CPL];
#pragma unroll
    for (int k = 0; k < CPL; k++) {
        float v = fmaf(acc[k], inv, bias[c0 + k]);
        v = (v >= 0.f) ? v : 0.01f * v;
        vals[k] = v;
    }
    {
        bf16x8 rr = *(const bf16x8*)(res + (size_t)n * HC + c0);
#pragma unroll
        for (int k = 0; k < CPL; k++) {
            vals[k] += sb2f(rr[k]);
            ls += vals[k];
            ls2 += vals[k] * vals[k];
        }
    }
    bf16x8 ov;
#pragma unroll
    for (int k = 0; k < 8; k++) ov[k] = f2bs(vals[k]);
    *(bf16x8*)(out_b + (size_t)n * HC + c0) = ov;

#pragma unroll
    for (int msk = 32; msk; msk >>= 1) {
        ls += __shfl_xor(ls, msk);
        ls2 += __shfl_xor(ls2, msk);
    }
    if (lane == 0) {
        int g = n >> 8;
        atomicAdd(&lnsums[g], ls);
        atomicAdd(&lnsums[BBG + g], ls2);
    }
}

// ---------------------------------------------------------------------------
// LN apply + channel-wise online-softmax aggregation (bf16 h), partials.
// ---------------------------------------------------------------------------
__global__ __launch_bounds__(256) void aggr_partial(
    const bf16* __restrict__ h, const float* __restrict__ lnsums,
    const float* __restrict__ lnw, const float* __restrict__ lnb,
    const float* __restrict__ t_, float* __restrict__ pm,
    float* __restrict__ pd, float* __restrict__ pa)
{
    int g = blockIdx.x, ch = blockIdx.y, nk = blockIdx.z;
    int tid = threadIdx.x;
    int c = ch * 256 + tid;
    const float tot = (float)(NG * DD);
    float S = lnsums[g], S2 = lnsums[BBG + g];
    float mu = S / tot;
    float iv = rsqrtf(fmaxf(S2 / tot - mu * mu, 0.f) + 1e-5f);
    float w = lnw[c], b = lnb[c], t = t_[0];
    size_t base = (size_t)g * NG * DD + (size_t)nk * 32 * DD + c;
    float m = -1e30f, den = 0.f, acc = 0.f;
    for (int i = 0; i < 32; i++) {
        float hn = (b2f(h[base + (size_t)i * DD]) - mu) * iv * w + b;
        float lg = hn * t;
        if (lg > m) {
            float r = __expf(m - lg);
            den *= r; acc *= r; m = lg;
        }
        float p = __expf(lg - m);
        den += p; acc += p * hn;
    }
    size_t idx = (((size_t)g * 2 + ch) * 8 + nk) * 256 + tid;
    pm[idx] = m; pd[idx] = den; pa[idx] = acc;
}

__global__ __launch_bounds__(256) void aggr_combine(
    const float* __restrict__ pm, const float* __restrict__ pd,
    const float* __restrict__ pa, float* __restrict__ gout)
{
    int g = blockIdx.x, ch = blockIdx.y;
    int tid = threadIdx.x;
    size_t base = (((size_t)g * 2 + ch) * 8) * 256 + tid;
    float m = -1e30f;
#pragma unroll
    for (int k = 0; k < 8; k++) m = fmaxf(m, pm[base + k * 256]);
    float den = 0.f, acc = 0.f;
#pragma unroll
    for (int k = 0; k < 8; k++) {
        float r = __expf(pm[base + k * 256] - m);
        den += pd[base + k * 256] * r;
        acc += pa[base + k * 256] * r;
    }
    gout[(size_t)g * DD + ch * 256 + tid] = acc / den;
}

// ---------------------------------------------------------------------------
extern "C" void kernel_launch(void* const* d_in, const int* in_sizes, int n_in,
                              void* d_out, int out_size, void* d_ws, size_t ws_size,
                              hipStream_t stream)
{
    const float* x      = (const float*)d_in[0];
    const int*   ei     = (const int*)d_in[1];
    const float* xt_w1  = (const float*)d_in[3];
    const float* xt_b1  = (const float*)d_in[4];
    const float* xt_w2  = (const float*)d_in[5];
    const float* xt_b2  = (const float*)d_in[6];
    const float* ln_w   = (const float*)d_in[27];
    const float* ln_b   = (const float*)d_in[28];
    const float* aggr_t = (const float*)d_in[29];
    const float* m_w1   = (const float*)d_in[30];
    const float* m_b1   = (const float*)d_in[31];
    const float* m_w2   = (const float*)d_in[32];
    const float* m_b2   = (const float*)d_in[33];
    const float* m_w3   = (const float*)d_in[34];
    const float* m_b3   = (const float*)d_in[35];
    float* out = (float*)d_out;

    // ---- workspace layout (256B aligned); ints first ----
    char* p = (char*)d_ws;
    auto take = [&](size_t bytes) {
        char* r = p;
        p += (bytes + 255) & ~(size_t)255;
        return r;
    };
    int* i_cur     = (int*)take((size_t)NN * 4);
    int* i_src     = (int*)take((size_t)NN * 64 * 4);        // bucket CSR
    float* f_sums  = (float*)take((size_t)2 * BBG * 4);
    float* f_pm    = (float*)take((size_t)BBG * 2 * 8 * 256 * 4);
    float* f_pd    = (float*)take((size_t)BBG * 2 * 8 * 256 * 4);
    float* f_pa    = (float*)take((size_t)BBG * 2 * 8 * 256 * 4);
    float* b_g     = (float*)take((size_t)BBG * DD * 4);
    float* b_m1    = (float*)take((size_t)BBG * 384 * 4);
    float* b_m2    = (float*)take((size_t)BBG * 256 * 4);
    bf16* b_resb   = (bf16*)take((size_t)NN * DD * 2);       // bf16 cx/residual
    bf16* b_h      = (bf16*)take((size_t)NN * DD * 2);       // bf16 final h (L4)
    bf16* b_hb     = (bf16*)take((size_t)NN * 1024 * 2);     // bf16 h (alias t1b)
    bf16* b_xlb    = (bf16*)take((size_t)NN * 1024 * 2);     // bf16 xl
    bf16* b_xrb    = (bf16*)take((size_t)NN * 1024 * 2);     // bf16 xr
    unsigned char* b_xp = (unsigned char*)take((size_t)NN * RS1024); // packed fp8
    bf16* b_xb     = (bf16*)take((size_t)2 * NN * 32 * 2);
    bf16* b_wcat   = (bf16*)take((size_t)8 * 1024 * 1024 * 2); // all [wlT;wrT]
    bf16* b_w1b    = (bf16*)take((size_t)32 * 256 * 2);
    bf16* b_w2b    = (bf16*)take((size_t)256 * 256 * 2);
    bf16* b_t1b = b_hb;

    // wcat element offsets per layer
    size_t woff[5];
    {
        size_t o = 0;
        for (int L = 0; L < 5; L++) {
            int Fin = (L == 0) ? 512 : 1024;
            int HC  = (L == 4) ? 512 : 1024;
            woff[L] = o;
            o += (size_t)2 * HC * Fin;
        }
    }

    dim3 blk(256);

    // ---- bucket CSR + LN-sum zero ----
    hipMemsetAsync(i_cur, 0, (size_t)NN * 4, stream);
    hipMemsetAsync(f_sums, 0, (size_t)2 * BBG * 4, stream);
    fill_csr<<<ET / 256, blk, 0, stream>>>(ei, i_cur, i_src);

    // ---- x convert + ALL weight transposes in one launch ----
    f2b_vec<<<(2 * NN * 32 + 255) / 256, blk, 0, stream>>>(x, b_xb, 2 * NN * 32);
    {
        TPackAll pk;
        pk.in[0] = xt_w1; pk.out[0] = b_w1b; pk.R[0] = 32;  pk.C[0] = 256;
        pk.in[1] = xt_w2; pk.out[1] = b_w2b; pk.R[1] = 256; pk.C[1] = 256;
        for (int L = 0; L < 5; L++) {
            int Fin = (L == 0) ? 512 : 1024;
            int HC  = (L == 4) ? 512 : 1024;
            pk.in[2 + 2 * L] = (const float*)d_in[7 + 4 * L];      // wl
            pk.out[2 + 2 * L] = b_wcat + woff[L];
            pk.R[2 + 2 * L] = Fin; pk.C[2 + 2 * L] = HC;
            pk.in[3 + 2 * L] = (const float*)d_in[8 + 4 * L];      // wr
            pk.out[3 + 2 * L] = b_wcat + woff[L] + (size_t)HC * Fin;
            pk.R[3 + 2 * L] = Fin; pk.C[3 + 2 * L] = HC;
        }
        transpose_batch<<<dim3(32, 32, 12), blk, 0, stream>>>(pk);
    }

    // ---- x_trans ----
    gemm_mfma_bt<<<dim3(256 / 128, 32768 / 128), blk, 0, stream>>>(
        b_xb, b_w1b, xt_b1, b_t1b, 32768, 256, 32, 0.01f, 1);
    gemm_mfma_bt<<<dim3(256 / 128, 32768 / 128), blk, 0, stream>>>(
        b_t1b, b_w2b, xt_b2, b_resb, 32768, 256, 256, 0.f, 0);

    // ---- 5 GATv2 layers (all fp8 packed gathers) ----
    for (int L = 0; L < 5; L++) {
        const float* att = (const float*)d_in[9 + 4 * L];
        const float* gb  = (const float*)d_in[10 + 4 * L];
        int Fin = (L == 0) ? 512 : 1024;
        int HC  = (L == 4) ? 512 : 1024;
        const bf16* hin = (L == 0) ? b_resb : b_hb;

        gemm_mfma_dual<<<dim3(2 * HC / 128, NN / 128), blk, 0, stream>>>(
            hin, b_wcat + woff[L], b_xlb, b_xrb, NN, Fin, HC);
        if (L < 4) {
            quant1024<<<NN / 4, blk, 0, stream>>>(b_xlb, b_xp);
            gat_q<<<NN / 4, blk, 0, stream>>>(
                b_xp, b_xrb, att, gb, i_cur, i_src, b_hb);
        } else {
            quant512<<<NN / 4, blk, 0, stream>>>(b_xlb, b_xp);
            gat_q512<<<NN / 4, blk, 0, stream>>>(
                b_xp, b_xrb, att, gb, i_cur, i_src, b_resb, b_h, f_sums);
        }
    }

    // ---- graph LN + softmax aggregation ----
    aggr_partial<<<dim3(BBG, 2, 8), blk, 0, stream>>>(
        b_h, f_sums, ln_w, ln_b, aggr_t, f_pm, f_pd, f_pa);
    aggr_combine<<<dim3(BBG, 2), blk, 0, stream>>>(f_pm, f_pd, f_pa, b_g);

    // ---- head MLP 512 -> 384 -> 256 -> 128 (fp32) ----
    gemm_f32<<<dim3(384 / 64, 1), blk, 0, stream>>>(
        b_g, m_w1, m_b1, b_m1, 64, 384, 512, 0.01f, 1);
    gemm_f32<<<dim3(256 / 64, 1), blk, 0, stream>>>(
        b_m1, m_w2, m_b2, b_m2, 64, 256, 384, 0.01f, 1);
    gemm_f32<<<dim3(128 / 64, 1), blk, 0, stream>>>(
        b_m2, m_w3, m_b3, out, 64, 128, 256, 0.f, 0);
}

// Round 11
// 1043.818 us; speedup vs baseline: 1.1138x; 1.0182x over previous
//
#include <hip/hip_runtime.h>
#include <hip/hip_bf16.h>

typedef __hip_bfloat16 bf16;

#define NN 16384          // gate nodes
#define BBG 64            // graphs
#define EE 49152          // directed edges (no self loops)
#define ET (EE + NN)      // edges + self loops = 65536
#define DD 512            // node feature dim (2F)
#define NG (NN / BBG)     // 256 nodes per graph
#define RS1024 1152       // packed fp8 row stride, HC=1024: 128B scales + 1024B data
#define RS512  640        // packed fp8 row stride, HC=512:  128B scales + 512B data

__device__ __forceinline__ float b2f(bf16 v) { return __bfloat162float(v); }
__device__ __forceinline__ bf16 f2b(float v) { return __float2bfloat16(v); }
__device__ __forceinline__ float sb2f(short s) {
    unsigned u = ((unsigned)(unsigned short)s) << 16;
    return __builtin_bit_cast(float, u);
}
__device__ __forceinline__ short f2bs(float v) {
    bf16 b = f2b(v);
    return __builtin_bit_cast(short, b);
}
__device__ __forceinline__ int clampi(int v, int lo, int hi)
{
    return v < lo ? lo : (v > hi ? hi : v);
}

// ---- OCP e4m3fn encode/decode (manual, self-contained) ----
__device__ __forceinline__ unsigned char enc_e4m3(float y)
{
    unsigned b = __builtin_bit_cast(unsigned, y);
    unsigned s = (b >> 31) << 7;
    float a = fabsf(y);
    unsigned ab = b & 0x7fffffffu;
    unsigned rb = ab + (1u << 19);            // round half-up at mantissa bit 20
    int e = (int)(rb >> 23) - 120;
    unsigned m = (rb >> 20) & 7u;
    unsigned qn = (unsigned)(e << 3) | m;
    if (qn > 126u) qn = 126u;                 // clamp to 448, never NaN encoding
    unsigned qd = (unsigned)__float2int_rn(a * 512.f);  // denormal
    unsigned q = (a < 0.015625f) ? qd : qn;
    return (unsigned char)(q | s);
}
__device__ __forceinline__ float dec_e4m3(unsigned q)
{
    unsigned e = (q >> 3) & 15u, m = q & 7u;
    float nrm = __builtin_bit_cast(float, ((e + 120u) << 23) | (m << 20));
    float dnm = (float)m * 0.001953125f;      // m * 2^-9
    float v = e ? nrm : dnm;
    return (q & 128u) ? -v : v;
}

typedef __attribute__((ext_vector_type(8))) short bf16x8;  // 8 bf16 = 4 VGPRs
typedef __attribute__((ext_vector_type(4))) float f32x4;

#define AS1 __attribute__((address_space(1)))
#define AS3 __attribute__((address_space(3)))

// ---------------------------------------------------------------------------
// MFMA bf16 GEMM: C = act(A @ Bt^T + bias). Used for x_trans.
// ---------------------------------------------------------------------------
__global__ __launch_bounds__(256) void gemm_mfma_bt(
    const bf16* __restrict__ A, const bf16* __restrict__ Bt,
    const float* __restrict__ bias, bf16* __restrict__ Cb,
    int M, int N, int K, float slope, int has_act)
{
    __shared__ bf16 As[128 * 32];
    __shared__ bf16 Bs[128 * 32];
    const int tid = threadIdx.x;
    const int w = tid >> 6;
    const int l = tid & 63;
    const int bm = blockIdx.y * 128;
    const int bn = blockIdx.x * 128;
    const int wrow = (w >> 1) * 64;
    const int wcol = (w & 1) * 64;
    const int quad = l >> 4;
    const int c16 = l & 15;

    const int lrow = l >> 2;
    const int lchunk = l & 3;
    const bf16* Ag = A + (size_t)(bm + w * 16 + lrow) * K + lchunk * 8;
    const bf16* Bg = Bt + (size_t)(bn + w * 16 + lrow) * K + lchunk * 8;
    char* AsB = (char*)As;
    char* BsB = (char*)Bs;

    f32x4 acc[4][4] = {};

    for (int k0 = 0; k0 < K; k0 += 32) {
        __builtin_amdgcn_global_load_lds((const AS1 void*)(Ag + k0),
            (AS3 void*)(AsB + w * 1024), 16, 0, 0);
        __builtin_amdgcn_global_load_lds((const AS1 void*)(Ag + (size_t)64 * K + k0),
            (AS3 void*)(AsB + 4096 + w * 1024), 16, 0, 0);
        __builtin_amdgcn_global_load_lds((const AS1 void*)(Bg + k0),
            (AS3 void*)(BsB + w * 1024), 16, 0, 0);
        __builtin_amdgcn_global_load_lds((const AS1 void*)(Bg + (size_t)64 * K + k0),
            (AS3 void*)(BsB + 4096 + w * 1024), 16, 0, 0);
        __syncthreads();

        bf16x8 a[4], b[4];
#pragma unroll
        for (int i = 0; i < 4; i++) {
            int ra = wrow + i * 16 + c16;
            a[i] = *(const bf16x8*)(AsB + ra * 64 + quad * 16);
            int rb = wcol + i * 16 + c16;
            b[i] = *(const bf16x8*)(BsB + rb * 64 + quad * 16);
        }
#pragma unroll
        for (int i = 0; i < 4; i++)
#pragma unroll
            for (int j = 0; j < 4; j++)
                acc[i][j] = __builtin_amdgcn_mfma_f32_16x16x32_bf16(
                    a[i], b[j], acc[i][j], 0, 0, 0);
        __syncthreads();
    }

#pragma unroll
    for (int i = 0; i < 4; i++) {
#pragma unroll
        for (int j = 0; j < 4; j++) {
            int col = bn + wcol + j * 16 + c16;
            float bv = bias ? bias[col] : 0.f;
#pragma unroll
            for (int r = 0; r < 4; r++) {
                int row = bm + wrow + i * 16 + quad * 4 + r;
                float v = acc[i][j][r] + bv;
                if (has_act) v = (v >= 0.f) ? v : v * slope;
                Cb[(size_t)row * N + col] = f2b(v);
            }
        }
    }
}

// ---------------------------------------------------------------------------
// Merged dual GEMM with XCD-AWARE SWIZZLE. Bt = [wlT; wrT]. M == NN (128
// M-blocks). 1-D grid, id%8 = XCD (heuristic): each XCD owns 16 contiguous
// M-blocks and iterates all N-blocks within them -> A-tile (256KB) stays
// L2-resident, W (<=4MB) ~ one L2. Targets R8's 137MB FETCH_SIZE.
// ---------------------------------------------------------------------------
__global__ __launch_bounds__(256) void gemm_mfma_dual(
    const bf16* __restrict__ A, const bf16* __restrict__ Bt,
    bf16* __restrict__ X0, bf16* __restrict__ X1,
    int K, int HC)
{
    const int NBX = HC >> 6;            // 2*HC/128 N-blocks
    const int id = blockIdx.x;
    const int xcd = id & 7;
    const int s = id >> 3;
    const int by = xcd * 16 + s / NBX;  // M-block (NN/128 = 128 total)
    const int bx = s % NBX;

    __shared__ bf16 As[128 * 32];
    __shared__ bf16 Bs[128 * 32];
    const int tid = threadIdx.x;
    const int w = tid >> 6;
    const int l = tid & 63;
    const int bm = by * 128;
    const int bn = bx * 128;
    const int wrow = (w >> 1) * 64;
    const int wcol = (w & 1) * 64;
    const int quad = l >> 4;
    const int c16 = l & 15;

    const int lrow = l >> 2;
    const int lchunk = l & 3;
    const bf16* Ag = A + (size_t)(bm + w * 16 + lrow) * K + lchunk * 8;
    const bf16* Bg = Bt + (size_t)(bn + w * 16 + lrow) * K + lchunk * 8;
    char* AsB = (char*)As;
    char* BsB = (char*)Bs;

    f32x4 acc[4][4] = {};

    for (int k0 = 0; k0 < K; k0 += 32) {
        __builtin_amdgcn_global_load_lds((const AS1 void*)(Ag + k0),
            (AS3 void*)(AsB + w * 1024), 16, 0, 0);
        __builtin_amdgcn_global_load_lds((const AS1 void*)(Ag + (size_t)64 * K + k0),
            (AS3 void*)(AsB + 4096 + w * 1024), 16, 0, 0);
        __builtin_amdgcn_global_load_lds((const AS1 void*)(Bg + k0),
            (AS3 void*)(BsB + w * 1024), 16, 0, 0);
        __builtin_amdgcn_global_load_lds((const AS1 void*)(Bg + (size_t)64 * K + k0),
            (AS3 void*)(BsB + 4096 + w * 1024), 16, 0, 0);
        __syncthreads();

        bf16x8 a[4], b[4];
#pragma unroll
        for (int i = 0; i < 4; i++) {
            int ra = wrow + i * 16 + c16;
            a[i] = *(const bf16x8*)(AsB + ra * 64 + quad * 16);
            int rb = wcol + i * 16 + c16;
            b[i] = *(const bf16x8*)(BsB + rb * 64 + quad * 16);
        }
#pragma unroll
        for (int i = 0; i < 4; i++)
#pragma unroll
            for (int j = 0; j < 4; j++)
                acc[i][j] = __builtin_amdgcn_mfma_f32_16x16x32_bf16(
                    a[i], b[j], acc[i][j], 0, 0, 0);
        __syncthreads();
    }

#pragma unroll
    for (int i = 0; i < 4; i++) {
#pragma unroll
        for (int j = 0; j < 4; j++) {
            int col = bn + wcol + j * 16 + c16;
            bf16* dst = (col < HC) ? (X0 + col) : (X1 + col - HC);
#pragma unroll
            for (int r = 0; r < 4; r++) {
                int row = bm + wrow + i * 16 + quad * 4 + r;
                dst[(size_t)row * HC] = f2b(acc[i][j][r]);
            }
        }
    }
}

// ---------------------------------------------------------------------------
// Row quantizers -> PACKED rows: [scales bf16 x64 | fp8 data]
// ---------------------------------------------------------------------------
__global__ __launch_bounds__(256, 4) void quant1024(
    const bf16* __restrict__ xl, unsigned char* __restrict__ xp)
{
    const int n = blockIdx.x * 4 + (threadIdx.x >> 6);
    const int lane = threadIdx.x & 63;
    const bf16* rp = xl + (size_t)n * 1024 + lane * 16;
    bf16x8 v0 = *(const bf16x8*)(rp);
    bf16x8 v1 = *(const bf16x8*)(rp + 8);
    float x[16];
#pragma unroll
    for (int k = 0; k < 8; k++) { x[k] = sb2f(v0[k]); x[8 + k] = sb2f(v1[k]); }
    float mx = 0.f;
#pragma unroll
    for (int k = 0; k < 16; k++) mx = fmaxf(mx, fabsf(x[k]));
    float sc = b2f(f2b(fmaxf(mx, 1e-20f) * (1.f / 448.f)));
    float isc = 1.f / sc;
    uint4 q;
    unsigned* qw = (unsigned*)&q;
#pragma unroll
    for (int w = 0; w < 4; w++) {
        unsigned pk = 0;
#pragma unroll
        for (int b = 0; b < 4; b++)
            pk |= ((unsigned)enc_e4m3(x[w * 4 + b] * isc)) << (b * 8);
        qw[w] = pk;
    }
    unsigned char* row = xp + (size_t)n * RS1024;
    *(uint4*)(row + 128 + lane * 16) = q;
    ((bf16*)row)[lane] = f2b(sc);
}

__global__ __launch_bounds__(256, 4) void quant512(
    const bf16* __restrict__ xl, unsigned char* __restrict__ xp)
{
    const int n = blockIdx.x * 4 + (threadIdx.x >> 6);
    const int lane = threadIdx.x & 63;
    bf16x8 v0 = *(const bf16x8*)(xl + (size_t)n * 512 + lane * 8);
    float x[8];
#pragma unroll
    for (int k = 0; k < 8; k++) x[k] = sb2f(v0[k]);
    float mx = 0.f;
#pragma unroll
    for (int k = 0; k < 8; k++) mx = fmaxf(mx, fabsf(x[k]));
    float sc = b2f(f2b(fmaxf(mx, 1e-20f) * (1.f / 448.f)));
    float isc = 1.f / sc;
    uint2 q;
    unsigned* qw = (unsigned*)&q;
#pragma unroll
    for (int w = 0; w < 2; w++) {
        unsigned pk = 0;
#pragma unroll
        for (int b = 0; b < 4; b++)
            pk |= ((unsigned)enc_e4m3(x[w * 4 + b] * isc)) << (b * 8);
        qw[w] = pk;
    }
    unsigned char* row = xp + (size_t)n * RS512;
    *(uint2*)(row + 128 + lane * 8) = q;
    ((bf16*)row)[lane] = f2b(sc);
}

// ---------------------------------------------------------------------------
// fp32 GEMM (head MLP only)
// ---------------------------------------------------------------------------
__global__ __launch_bounds__(256) void gemm_f32(
    const float* __restrict__ A, const float* __restrict__ W,
    const float* __restrict__ bias, float* __restrict__ C,
    int M, int N, int K, float slope, int has_act)
{
    const int BK = 16;
    __shared__ float Asm[BK][64 + 1];
    __shared__ float Wsm[BK][64 + 1];
    int tid = threadIdx.x;
    int bm = blockIdx.y * 64;
    int bn = blockIdx.x * 64;
    int tr = tid >> 4;
    int tc = tid & 15;
    float acc[4][4] = {};

    for (int k0 = 0; k0 < K; k0 += BK) {
        {
            int col = tid & 15;
            int row = tid >> 4;
#pragma unroll
            for (int p = 0; p < 4; p++) {
                int r = row + p * 16;
                Asm[col][r] = A[(size_t)(bm + r) * K + k0 + col];
            }
        }
        {
            int wc = tid & 63;
            int wr = tid >> 6;
#pragma unroll
            for (int p = 0; p < 4; p++) {
                int r = wr + p * 4;
                Wsm[r][wc] = W[(size_t)(k0 + r) * N + bn + wc];
            }
        }
        __syncthreads();
#pragma unroll
        for (int kk = 0; kk < BK; kk++) {
            float a[4], w[4];
#pragma unroll
            for (int i = 0; i < 4; i++) a[i] = Asm[kk][tr * 4 + i];
#pragma unroll
            for (int j = 0; j < 4; j++) w[j] = Wsm[kk][tc * 4 + j];
#pragma unroll
            for (int i = 0; i < 4; i++)
#pragma unroll
                for (int j = 0; j < 4; j++)
                    acc[i][j] += a[i] * w[j];
        }
        __syncthreads();
    }
#pragma unroll
    for (int i = 0; i < 4; i++) {
        int r = bm + tr * 4 + i;
#pragma unroll
        for (int j = 0; j < 4; j++) {
            int cn = bn + tc * 4 + j;
            float v = acc[i][j];
            if (bias) v += bias[cn];
            if (has_act) v = (v >= 0.f) ? v : v * slope;
            C[(size_t)r * N + cn] = v;
        }
    }
}

// ---------------------------------------------------------------------------
// Batched fp32 [R,C] -> bf16 [C,R] transpose-convert, 12 slices in one launch
// ---------------------------------------------------------------------------
struct TPackAll {
    const float* in[12];
    bf16* out[12];
    int R[12], C[12];
};

__global__ __launch_bounds__(256) void transpose_batch(TPackAll pk)
{
    int z = blockIdx.z;
    int R = pk.R[z], C = pk.C[z];
    int c0 = blockIdx.x * 32;
    int r0 = blockIdx.y * 32;
    if (c0 >= C || r0 >= R) return;
    const float* in = pk.in[z];
    bf16* out = pk.out[z];
    __shared__ float tile[32][33];
    int tx = threadIdx.x & 31;
    int ty = threadIdx.x >> 5;
#pragma unroll
    for (int k = 0; k < 4; k++) {
        int r = ty + k * 8;
        tile[r][tx] = in[(size_t)(r0 + r) * C + c0 + tx];
    }
    __syncthreads();
#pragma unroll
    for (int k = 0; k < 4; k++) {
        int rr = ty + k * 8;
        out[(size_t)(c0 + rr) * R + r0 + tx] = f2b(tile[tx][rr]);
    }
}

__global__ void f2b_vec(const float* __restrict__ in, bf16* __restrict__ out, int n)
{
    int i = blockIdx.x * 256 + threadIdx.x;
    if (i < n) out[i] = f2b(in[i]);
}

// ---------------------------------------------------------------------------
// Bucket CSR: csrc[d][64] slots, cur[d] = in-degree (incl self loop).
// ---------------------------------------------------------------------------
__global__ void fill_csr(const int* __restrict__ ei, int* __restrict__ cur,
                         int* __restrict__ csrc)
{
    int e = blockIdx.x * 256 + threadIdx.x;
    if (e >= ET) return;
    int s, d;
    if (e < EE) { s = ei[e]; d = ei[EE + e]; } else { s = d = e - EE; }
    s = clampi(s, 0, NN - 1);
    d = clampi(d, 0, NN - 1);
    int pos = atomicAdd(&cur[d], 1);
    if (pos < 64) csrc[d * 64 + pos] = s;
}

// ---------------------------------------------------------------------------
// Counting sort of nodes by degree -> order[]. Blocks then process 4
// equal-degree nodes, eliminating the max-deg tail wait (deg ~ Poisson(3)+1:
// E[max of 4 random] ~ 7-8 vs sorted ~ 4). Single block, 2 passes.
// ---------------------------------------------------------------------------
__global__ __launch_bounds__(256) void sort_nodes(
    const int* __restrict__ cur, int* __restrict__ order)
{
    __shared__ int cnt[65], base[65];
    int tid = threadIdx.x;
    if (tid < 65) cnt[tid] = 0;
    __syncthreads();
    for (int n = tid; n < NN; n += 256)
        atomicAdd(&cnt[clampi(cur[n], 0, 64)], 1);
    __syncthreads();
    if (tid == 0) {
        int a = 0;
        for (int d = 0; d <= 64; d++) { base[d] = a; a += cnt[d]; }
    }
    __syncthreads();
    for (int n = tid; n < NN; n += 256) {
        int d = clampi(cur[n], 0, 64);
        int pos = atomicAdd(&base[d], 1);
        order[clampi(pos, 0, NN - 1)] = n;
    }
}

// ---------------------------------------------------------------------------
// GATv2 edge phase, packed-fp8 gathers, HC=1024 (2 heads). Wave-per-node
// (degree-sorted order), depth-3 rotation prefetch, online softmax.
// ---------------------------------------------------------------------------
__global__ __launch_bounds__(256, 4) void gat_q(
    const unsigned char* __restrict__ xp, const bf16* __restrict__ xr,
    const float* __restrict__ att, const float* __restrict__ bias,
    const int* __restrict__ cur, const int* __restrict__ csrc,
    const int* __restrict__ order, bf16* __restrict__ out_b)
{
    constexpr int HC = 1024, CPL = 16;
    const int tid = threadIdx.x;
    const int w = tid >> 6;
    const int lane = tid & 63;
    const int n = clampi(order[blockIdx.x * 4 + w], 0, NN - 1);
    const int c0 = lane * CPL;

    int deg = clampi(cur[n], 1, 64);
    int my_src = clampi(csrc[n * 64 + lane], 0, NN - 1);

    float av[CPL], rv[CPL];
    {
        bf16x8 r0 = *(const bf16x8*)(xr + (size_t)n * HC + c0);
        bf16x8 r1 = *(const bf16x8*)(xr + (size_t)n * HC + c0 + 8);
#pragma unroll
        for (int k = 0; k < 8; k++) { rv[k] = sb2f(r0[k]); rv[8 + k] = sb2f(r1[k]); }
#pragma unroll
        for (int k = 0; k < CPL; k++) av[k] = att[c0 + k];
    }

    float m = -1e30f, den = 0.f;
    float acc[CPL];
#pragma unroll
    for (int k = 0; k < CPL; k++) acc[k] = 0.f;

    auto loadrow = [&](int i, uint4& q, float& sc) {
        int s = __shfl(my_src, i);
        const unsigned char* row = xp + (size_t)s * RS1024;
        sc = b2f(*(const bf16*)(row + lane * 2));
        q = *(const uint4*)(row + 128 + lane * 16);
    };
    auto process = [&](const uint4& q, float sc) {
        float x[CPL];
        const unsigned* qw = (const unsigned*)&q;
#pragma unroll
        for (int k = 0; k < CPL; k++)
            x[k] = dec_e4m3((qw[k >> 2] >> ((k & 3) * 8)) & 255u) * sc;
        float part = 0.f;
#pragma unroll
        for (int k = 0; k < CPL; k++) {
            float u = x[k] + rv[k];
            u = (u >= 0.f) ? u : 0.2f * u;
            part = fmaf(av[k], u, part);
        }
#pragma unroll
        for (int msk = 16; msk; msk >>= 1) part += __shfl_xor(part, msk);
        float lg = part;
        float mn = fmaxf(m, lg);
        float r = __expf(m - mn);
        float pi = __expf(lg - mn);
        m = mn;
        den = den * r + pi;
#pragma unroll
        for (int k = 0; k < CPL; k++) acc[k] = fmaf(acc[k], r, pi * x[k]);
    };

    uint4 cq, q1, q2, qn;
    float cs, s1, s2, sn;
    loadrow(0, cq, cs);
    if (deg > 1) loadrow(1, q1, s1);
    if (deg > 2) loadrow(2, q2, s2);
    for (int i = 0; i < deg; i++) {
        if (i + 3 < deg) loadrow(i + 3, qn, sn);
        process(cq, cs);
        cq = q1; cs = s1; q1 = q2; s1 = s2; q2 = qn; s2 = sn;
    }

    float inv = 1.f / den;
    bf16x8 ov0, ov1;
#pragma unroll
    for (int k = 0; k < 8; k++) {
        float v = fmaf(acc[k], inv, bias[c0 + k]);
        v = (v >= 0.f) ? v : 0.01f * v;
        ov0[k] = f2bs(v);
        float v2 = fmaf(acc[8 + k], inv, bias[c0 + 8 + k]);
        v2 = (v2 >= 0.f) ? v2 : 0.01f * v2;
        ov1[k] = f2bs(v2);
    }
    *(bf16x8*)(out_b + (size_t)n * HC + c0) = ov0;
    *(bf16x8*)(out_b + (size_t)n * HC + c0 + 8) = ov1;
}

// ---------------------------------------------------------------------------
// GATv2 edge phase, packed-fp8 gathers, HC=512 (1 head) + residual + LN sums.
// ---------------------------------------------------------------------------
__global__ __launch_bounds__(256, 4) void gat_q512(
    const unsigned char* __restrict__ xp, const bf16* __restrict__ xr,
    const float* __restrict__ att, const float* __restrict__ bias,
    const int* __restrict__ cur, const int* __restrict__ csrc,
    const int* __restrict__ order, const bf16* __restrict__ res,
    bf16* __restrict__ out_b, float* __restrict__ lnsums)
{
    constexpr int HC = 512, CPL = 8;
    const int tid = threadIdx.x;
    const int w = tid >> 6;
    const int lane = tid & 63;
    const int n = clampi(order[blockIdx.x * 4 + w], 0, NN - 1);
    const int c0 = lane * CPL;

    int deg = clampi(cur[n], 1, 64);
    int my_src = clampi(csrc[n * 64 + lane], 0, NN - 1);

    float av[CPL], rv[CPL];
    {
        bf16x8 rp = *(const bf16x8*)(xr + (size_t)n * HC + c0);
#pragma unroll
        for (int k = 0; k < CPL; k++) {
            rv[k] = sb2f(rp[k]);
            av[k] = att[c0 + k];
        }
    }

    float m = -1e30f, den = 0.f;
    float acc[CPL];
#pragma unroll
    for (int k = 0; k < CPL; k++) acc[k] = 0.f;

    auto loadrow = [&](int i, uint2& q, float& sc) {
        int s = __shfl(my_src, i);
        const unsigned char* row = xp + (size_t)s * RS512;
        sc = b2f(*(const bf16*)(row + lane * 2));
        q = *(const uint2*)(row + 128 + lane * 8);
    };
    auto process = [&](const uint2& q, float sc) {
        float x[CPL];
        const unsigned* qw = (const unsigned*)&q;
#pragma unroll
        for (int k = 0; k < CPL; k++)
            x[k] = dec_e4m3((qw[k >> 2] >> ((k & 3) * 8)) & 255u) * sc;
        float part = 0.f;
#pragma unroll
        for (int k = 0; k < CPL; k++) {
            float u = x[k] + rv[k];
            u = (u >= 0.f) ? u : 0.2f * u;
            part = fmaf(av[k], u, part);
        }
#pragma unroll
        for (int msk = 32; msk; msk >>= 1) part += __shfl_xor(part, msk);
        float lg = part;
        float mn = fmaxf(m, lg);
        float r = __expf(m - mn);
        float pi = __expf(lg - mn);
        m = mn;
        den = den * r + pi;
#pragma unroll
        for (int k = 0; k < CPL; k++) acc[k] = fmaf(acc[k], r, pi * x[k]);
    };

    uint2 cq, q1, q2, qn;
    float cs, s1, s2, sn;
    loadrow(0, cq, cs);
    if (deg > 1) loadrow(1, q1, s1);
    if (deg > 2) loadrow(2, q2, s2);
    for (int i = 0; i < deg; i++) {
        if (i + 3 < deg) loadrow(i + 3, qn, sn);
        process(cq, cs);
        cq = q1; cs = s1; q1 = q2; s1 = s2; q2 = qn; s2 = sn;
    }

    float inv = 1.f / den;
    float ls = 0.f, ls2 = 0.f;
    float vals[CPL];
#pragma unroll
    for (int k = 0; k < CPL; k++) {
        float v = fmaf(acc[k], inv, bias[c0 + k]);
        v = (v >= 0.f) ? v : 0.01f * v;
        vals[k] = v;
    }
    {
        bf16x8 rr = *(const bf16x8*)(res + (size_t)n * HC + c0);
#pragma unroll
        for (int k = 0; k < CPL; k++) {
            vals[k] += sb2f(rr[k]);
            ls += vals[k];
            ls2 += vals[k] * vals[k];
        }
    }
    bf16x8 ov;
#pragma unroll
    for (int k = 0; k < 8; k++) ov[k] = f2bs(vals[k]);
    *(bf16x8*)(out_b + (size_t)n * HC + c0) = ov;

#pragma unroll
    for (int msk = 32; msk; msk >>= 1) {
        ls += __shfl_xor(ls, msk);
        ls2 += __shfl_xor(ls2, msk);
    }
    if (lane == 0) {
        int g = n >> 8;
        atomicAdd(&lnsums[g], ls);
        atomicAdd(&lnsums[BBG + g], ls2);
    }
}

// ---------------------------------------------------------------------------
// LN apply + channel-wise online-softmax aggregation (bf16 h), partials.
// ---------------------------------------------------------------------------
__global__ __launch_bounds__(256) void aggr_partial(
    const bf16* __restrict__ h, const float* __restrict__ lnsums,
    const float* __restrict__ lnw, const float* __restrict__ lnb,
    const float* __restrict__ t_, float* __restrict__ pm,
    float* __restrict__ pd, float* __restrict__ pa)
{
    int g = blockIdx.x, ch = blockIdx.y, nk = blockIdx.z;
    int tid = threadIdx.x;
    int c = ch * 256 + tid;
    const float tot = (float)(NG * DD);
    float S = lnsums[g], S2 = lnsums[BBG + g];
    float mu = S / tot;
    float iv = rsqrtf(fmaxf(S2 / tot - mu * mu, 0.f) + 1e-5f);
    float w = lnw[c], b = lnb[c], t = t_[0];
    size_t base = (size_t)g * NG * DD + (size_t)nk * 32 * DD + c;
    float m = -1e30f, den = 0.f, acc = 0.f;
    for (int i = 0; i < 32; i++) {
        float hn = (b2f(h[base + (size_t)i * DD]) - mu) * iv * w + b;
        float lg = hn * t;
        if (lg > m) {
            float r = __expf(m - lg);
            den *= r; acc *= r; m = lg;
        }
        float p = __expf(lg - m);
        den += p; acc += p * hn;
    }
    size_t idx = (((size_t)g * 2 + ch) * 8 + nk) * 256 + tid;
    pm[idx] = m; pd[idx] = den; pa[idx] = acc;
}

__global__ __launch_bounds__(256) void aggr_combine(
    const float* __restrict__ pm, const float* __restrict__ pd,
    const float* __restrict__ pa, float* __restrict__ gout)
{
    int g = blockIdx.x, ch = blockIdx.y;
    int tid = threadIdx.x;
    size_t base = (((size_t)g * 2 + ch) * 8) * 256 + tid;
    float m = -1e30f;
#pragma unroll
    for (int k = 0; k < 8; k++) m = fmaxf(m, pm[base + k * 256]);
    float den = 0.f, acc = 0.f;
#pragma unroll
    for (int k = 0; k < 8; k++) {
        float r = __expf(pm[base + k * 256] - m);
        den += pd[base + k * 256] * r;
        acc += pa[base + k * 256] * r;
    }
    gout[(size_t)g * DD + ch * 256 + tid] = acc / den;
}

// ---------------------------------------------------------------------------
extern "C" void kernel_launch(void* const* d_in, const int* in_sizes, int n_in,
                              void* d_out, int out_size, void* d_ws, size_t ws_size,
                              hipStream_t stream)
{
    const float* x      = (const float*)d_in[0];
    const int*   ei     = (const int*)d_in[1];
    const float* xt_w1  = (const float*)d_in[3];
    const float* xt_b1  = (const float*)d_in[4];
    const float* xt_w2  = (const float*)d_in[5];
    const float* xt_b2  = (const float*)d_in[6];
    const float* ln_w   = (const float*)d_in[27];
    const float* ln_b   = (const float*)d_in[28];
    const float* aggr_t = (const float*)d_in[29];
    const float* m_w1   = (const float*)d_in[30];
    const float* m_b1   = (const float*)d_in[31];
    const float* m_w2   = (const float*)d_in[32];
    const float* m_b2   = (const float*)d_in[33];
    const float* m_w3   = (const float*)d_in[34];
    const float* m_b3   = (const float*)d_in[35];
    float* out = (float*)d_out;

    // ---- workspace layout (256B aligned); ints first ----
    char* p = (char*)d_ws;
    auto take = [&](size_t bytes) {
        char* r = p;
        p += (bytes + 255) & ~(size_t)255;
        return r;
    };
    int* i_cur     = (int*)take((size_t)NN * 4);
    int* i_src     = (int*)take((size_t)NN * 64 * 4);        // bucket CSR
    int* i_ord     = (int*)take((size_t)NN * 4);             // deg-sorted order
    float* f_sums  = (float*)take((size_t)2 * BBG * 4);
    float* f_pm    = (float*)take((size_t)BBG * 2 * 8 * 256 * 4);
    float* f_pd    = (float*)take((size_t)BBG * 2 * 8 * 256 * 4);
    float* f_pa    = (float*)take((size_t)BBG * 2 * 8 * 256 * 4);
    float* b_g     = (float*)take((size_t)BBG * DD * 4);
    float* b_m1    = (float*)take((size_t)BBG * 384 * 4);
    float* b_m2    = (float*)take((size_t)BBG * 256 * 4);
    bf16* b_resb   = (bf16*)take((size_t)NN * DD * 2);       // bf16 cx/residual
    bf16* b_h      = (bf16*)take((size_t)NN * DD * 2);       // bf16 final h (L4)
    bf16* b_hb     = (bf16*)take((size_t)NN * 1024 * 2);     // bf16 h (alias t1b)
    bf16* b_xlb    = (bf16*)take((size_t)NN * 1024 * 2);     // bf16 xl
    bf16* b_xrb    = (bf16*)take((size_t)NN * 1024 * 2);     // bf16 xr
    unsigned char* b_xp = (unsigned char*)take((size_t)NN * RS1024); // packed fp8
    bf16* b_xb     = (bf16*)take((size_t)2 * NN * 32 * 2);
    bf16* b_wcat   = (bf16*)take((size_t)8 * 1024 * 1024 * 2); // all [wlT;wrT]
    bf16* b_w1b    = (bf16*)take((size_t)32 * 256 * 2);
    bf16* b_w2b    = (bf16*)take((size_t)256 * 256 * 2);
    bf16* b_t1b = b_hb;

    // wcat element offsets per layer
    size_t woff[5];
    {
        size_t o = 0;
        for (int L = 0; L < 5; L++) {
            int Fin = (L == 0) ? 512 : 1024;
            int HC  = (L == 4) ? 512 : 1024;
            woff[L] = o;
            o += (size_t)2 * HC * Fin;
        }
    }

    dim3 blk(256);

    // ---- bucket CSR + degree sort + LN-sum zero ----
    hipMemsetAsync(i_cur, 0, (size_t)NN * 4, stream);
    hipMemsetAsync(f_sums, 0, (size_t)2 * BBG * 4, stream);
    fill_csr<<<ET / 256, blk, 0, stream>>>(ei, i_cur, i_src);
    sort_nodes<<<1, blk, 0, stream>>>(i_cur, i_ord);

    // ---- x convert + ALL weight transposes in one launch ----
    f2b_vec<<<(2 * NN * 32 + 255) / 256, blk, 0, stream>>>(x, b_xb, 2 * NN * 32);
    {
        TPackAll pk;
        pk.in[0] = xt_w1; pk.out[0] = b_w1b; pk.R[0] = 32;  pk.C[0] = 256;
        pk.in[1] = xt_w2; pk.out[1] = b_w2b; pk.R[1] = 256; pk.C[1] = 256;
        for (int L = 0; L < 5; L++) {
            int Fin = (L == 0) ? 512 : 1024;
            int HC  = (L == 4) ? 512 : 1024;
            pk.in[2 + 2 * L] = (const float*)d_in[7 + 4 * L];      // wl
            pk.out[2 + 2 * L] = b_wcat + woff[L];
            pk.R[2 + 2 * L] = Fin; pk.C[2 + 2 * L] = HC;
            pk.in[3 + 2 * L] = (const float*)d_in[8 + 4 * L];      // wr
            pk.out[3 + 2 * L] = b_wcat + woff[L] + (size_t)HC * Fin;
            pk.R[3 + 2 * L] = Fin; pk.C[3 + 2 * L] = HC;
        }
        transpose_batch<<<dim3(32, 32, 12), blk, 0, stream>>>(pk);
    }

    // ---- x_trans ----
    gemm_mfma_bt<<<dim3(256 / 128, 32768 / 128), blk, 0, stream>>>(
        b_xb, b_w1b, xt_b1, b_t1b, 32768, 256, 32, 0.01f, 1);
    gemm_mfma_bt<<<dim3(256 / 128, 32768 / 128), blk, 0, stream>>>(
        b_t1b, b_w2b, xt_b2, b_resb, 32768, 256, 256, 0.f, 0);

    // ---- 5 GATv2 layers (fp8 packed gathers, deg-sorted, swizzled GEMM) ----
    for (int L = 0; L < 5; L++) {
        const float* att = (const float*)d_in[9 + 4 * L];
        const float* gb  = (const float*)d_in[10 + 4 * L];
        int Fin = (L == 0) ? 512 : 1024;
        int HC  = (L == 4) ? 512 : 1024;
        const bf16* hin = (L == 0) ? b_resb : b_hb;
        int nblocks = (HC >> 6) * (NN / 128);   // NBX * M-blocks

        gemm_mfma_dual<<<dim3(nblocks), blk, 0, stream>>>(
            hin, b_wcat + woff[L], b_xlb, b_xrb, Fin, HC);
        if (L < 4) {
            quant1024<<<NN / 4, blk, 0, stream>>>(b_xlb, b_xp);
            gat_q<<<NN / 4, blk, 0, stream>>>(
                b_xp, b_xrb, att, gb, i_cur, i_src, i_ord, b_hb);
        } else {
            quant512<<<NN / 4, blk, 0, stream>>>(b_xlb, b_xp);
            gat_q512<<<NN / 4, blk, 0, stream>>>(
                b_xp, b_xrb, att, gb, i_cur, i_src, i_ord, b_resb, b_h, f_sums);
        }
    }

    // ---- graph LN + softmax aggregation ----
    aggr_partial<<<dim3(BBG, 2, 8), blk, 0, stream>>>(
        b_h, f_sums, ln_w, ln_b, aggr_t, f_pm, f_pd, f_pa);
    aggr_combine<<<dim3(BBG, 2), blk, 0, stream>>>(f_pm, f_pd, f_pa, b_g);

    // ---- head MLP 512 -> 384 -> 256 -> 128 (fp32) ----
    gemm_f32<<<dim3(384 / 64, 1), blk, 0, stream>>>(
        b_g, m_w1, m_b1, b_m1, 64, 384, 512, 0.01f, 1);
    gemm_f32<<<dim3(256 / 64, 1), blk, 0, stream>>>(
        b_m1, m_w2, m_b2, b_m2, 64, 256, 384, 0.01f, 1);
    gemm_f32<<<dim3(128 / 64, 1), blk, 0, stream>>>(
        b_m2, m_w3, m_b3, out, 64, 128, 256, 0.f, 0);
}